// Round 1
// baseline (434.599 us; speedup 1.0000x reference)
//
#include <hip/hip_runtime.h>
#include <math.h>

#define BB 8
#define CIN 64
#define CO 128
#define NPT 2048
#define KK 16
#define EPSV 1e-5f

typedef unsigned int u32;
typedef unsigned long long u64;

__device__ __forceinline__ u64 packdm(float f, int m) {
  // sortable-float key (monotonic increasing in f) in high 32 bits,
  // (0xFFFFFFFF - m) in low 32 bits: max() picks max value, ties -> min index.
  u32 u = __float_as_uint(f);
  u = (u & 0x80000000u) ? ~u : (u | 0x80000000u);
  return ((u64)u << 32) | (u64)(0xFFFFFFFFu - (u32)m);
}

__device__ __forceinline__ u64 umax64(u64 a, u64 b) { return a > b ? a : b; }

__device__ __forceinline__ u64 shfl_xor_u64(u64 x, int mask) {
  int lo = __shfl_xor((int)(u32)x, mask, 64);
  int hi = __shfl_xor((int)(u32)(x >> 32), mask, 64);
  return ((u64)(u32)hi << 32) | (u64)(u32)lo;
}

// ---------------------------------------------------------------------------
// Kernel A: transpose x (B,C,N) -> ft (B,N,C) and compute sq[b][n] = sum_c x^2
// ---------------------------------------------------------------------------
__global__ __launch_bounds__(256) void k_transpose_sq(
    const float* __restrict__ x, float* __restrict__ ft, float* __restrict__ sq) {
  __shared__ float tile[64][65];
  __shared__ float psum[4][64];
  int bid = blockIdx.x;           // B * (N/64) = 256
  int b = bid >> 5;
  int n0 = (bid & 31) << 6;
  int tid = threadIdx.x;
  int q = tid >> 6, lo = tid & 63;
#pragma unroll
  for (int i = 0; i < 16; ++i) {
    int c = i * 4 + q;
    tile[c][lo] = x[((size_t)(b * CIN + c)) * NPT + n0 + lo];
  }
  __syncthreads();
  float ps = 0.f;
#pragma unroll
  for (int i = 0; i < 16; ++i) {
    float t = tile[q * 16 + i][lo];
    ps += t * t;
  }
  psum[q][lo] = ps;
#pragma unroll
  for (int i = 0; i < 16; ++i) {
    int ni = i * 4 + q;
    ft[((size_t)(b * NPT + n0 + ni)) * CIN + lo] = tile[lo][ni];
  }
  __syncthreads();
  if (q == 0) {
    sq[(size_t)b * NPT + n0 + lo] = psum[0][lo] + psum[1][lo] + psum[2][lo] + psum[3][lo];
  }
}

// ---------------------------------------------------------------------------
// Kernel P: node-level matmuls
//   p[b][n][o] = sum_c x[c]*(W[o][c]-W[o][64+c]) + bias[o]
//   v[b][n][o] = sum_c x[c]*W[o][64+c]
// then h_edge = relu(p[i] + v[j])
// ---------------------------------------------------------------------------
__global__ __launch_bounds__(256) void k_pv(
    const float* __restrict__ ft, const float* __restrict__ W,
    const float* __restrict__ bias, float* __restrict__ p, float* __restrict__ v) {
  __shared__ float xl[32][64];
  int bid = blockIdx.x;           // B * (N/32) = 512
  int b = bid >> 6;
  int n0 = (bid & 63) << 5;
  int tid = threadIdx.x;
  for (int i = tid; i < 32 * 64; i += 256) {
    xl[i >> 6][i & 63] = ft[((size_t)(b * NPT + n0 + (i >> 6))) * CIN + (i & 63)];
  }
  __syncthreads();
  int o = tid & 127, hh = tid >> 7;
  const float4* W1 = (const float4*)&W[o * 2 * CIN];
  const float4* W2 = (const float4*)&W[o * 2 * CIN + CIN];
  float bo = bias[o];
#pragma unroll 1
  for (int t = 0; t < 16; ++t) {
    int node = t * 2 + hh;
    float a1 = 0.f, a2 = 0.f;
#pragma unroll
    for (int c4 = 0; c4 < 16; ++c4) {
      float4 xv = *(const float4*)&xl[node][c4 * 4];
      float4 w1 = W1[c4];
      float4 w2 = W2[c4];
      a1 += xv.x * w1.x + xv.y * w1.y + xv.z * w1.z + xv.w * w1.w;
      a2 += xv.x * w2.x + xv.y * w2.y + xv.z * w2.z + xv.w * w2.w;
    }
    size_t gn = ((size_t)(b * NPT + n0 + node)) * CO + o;
    p[gn] = a1 - a2 + bo;
    v[gn] = a2;
  }
}

// ---------------------------------------------------------------------------
// Kernel B: pairwise pd = 2*gram - sq_i - sq_j (8 rows per block, all 2048
// cols in LDS), then top-16 per row via chunk-owner argmax (32 lanes/row).
// ---------------------------------------------------------------------------
__global__ __launch_bounds__(256) void k_dist_topk(
    const float* __restrict__ ft, const float* __restrict__ sq,
    int* __restrict__ idxout) {
  __shared__ float dist[8][NPT];   // 64 KB
  int bid = blockIdx.x;            // B * (N/8) = 2048
  int b = bid >> 8;
  int n0 = (bid & 255) << 3;
  int tid = threadIdx.x;
  const float* fb = ft + (size_t)b * NPT * CIN;
  const float* sqb = sq + (size_t)b * NPT;

#pragma unroll 1
  for (int j = 0; j < 8; ++j) {
    int m = j * 256 + tid;
    float4 xm[16];
    const float4* src = (const float4*)&fb[(size_t)m * CIN];
#pragma unroll
    for (int c4 = 0; c4 < 16; ++c4) xm[c4] = src[c4];
    float sqm = sqb[m];
#pragma unroll 1
    for (int r = 0; r < 8; ++r) {
      const float4* xnrow = (const float4*)&fb[(size_t)(n0 + r) * CIN];  // uniform, L1-hot
      float4 a = {0.f, 0.f, 0.f, 0.f};
#pragma unroll
      for (int c4 = 0; c4 < 16; ++c4) {
        float4 xn = xnrow[c4];
        float4 mv = xm[c4];
        a.x += xn.x * mv.x;
        a.y += xn.y * mv.y;
        a.z += xn.z * mv.z;
        a.w += xn.w * mv.w;
      }
      float sqnr = sqb[n0 + r];  // uniform
      dist[r][m] = 2.f * (a.x + a.y + a.z + a.w) - sqnr - sqm;
    }
  }
  __syncthreads();

  // top-16: wave w handles rows 2w, 2w+1; 32 lanes per row; lane t owns
  // elements m == t (mod 32).
  int lane = tid & 63;
  int w = tid >> 6;
  int r = w * 2 + (lane >> 5);
  int t = lane & 31;

  u64 best = 0;
#pragma unroll 1
  for (int i = 0; i < 64; ++i) {
    int m = i * 32 + t;
    best = umax64(best, packdm(dist[r][m], m));
  }
  int* myidx = idxout + ((size_t)(b * NPT + n0 + r)) * KK;
#pragma unroll 1
  for (int it = 0; it < KK; ++it) {
    u64 vv = best;
#pragma unroll
    for (int s = 1; s <= 16; s <<= 1) {
      vv = umax64(vv, shfl_xor_u64(vv, s));  // stays within the 32-lane group
    }
    int mwin = (int)(0xFFFFFFFFu - (u32)vv);
    if (t == (mwin & 31)) {
      dist[r][mwin] = -__builtin_inff();
      u64 nb = 0;
      for (int i = 0; i < 64; ++i) {
        int m = i * 32 + t;
        nb = umax64(nb, packdm(dist[r][m], m));
      }
      best = nb;
    }
    if (t == 0) myidx[it] = mwin;
  }
}

// ---------------------------------------------------------------------------
// Kernel C: per-block partial sums of h and h^2 per channel (deterministic).
// ---------------------------------------------------------------------------
__global__ __launch_bounds__(256) void k_stats(
    const float* __restrict__ p, const float* __restrict__ v,
    const int* __restrict__ idx, float* __restrict__ psums,
    float* __restrict__ psqs) {
  __shared__ float rs[8][CO];
  __shared__ float rq[8][CO];
  int bid = blockIdx.x;            // B * (N/32) = 512
  int b = bid >> 6;
  int n0 = (bid & 63) << 5;
  int tid = threadIdx.x;
  int o4 = tid & 31, ns = tid >> 5;
  const float* vb = v + (size_t)b * NPT * CO;
  float4 s = {0.f, 0.f, 0.f, 0.f};
  float4 qq = {0.f, 0.f, 0.f, 0.f};
#pragma unroll 1
  for (int g = 0; g < 4; ++g) {
    int gn = b * NPT + n0 + g * 8 + ns;
    float4 p4 = *(const float4*)(p + (size_t)gn * CO + o4 * 4);
    const int* id = idx + (size_t)gn * KK;
#pragma unroll 1
    for (int k = 0; k < KK; ++k) {
      int j = id[k];
      float4 v4 = *(const float4*)(vb + (size_t)j * CO + o4 * 4);
      float h0 = fmaxf(p4.x + v4.x, 0.f);
      float h1 = fmaxf(p4.y + v4.y, 0.f);
      float h2 = fmaxf(p4.z + v4.z, 0.f);
      float h3 = fmaxf(p4.w + v4.w, 0.f);
      s.x += h0; s.y += h1; s.z += h2; s.w += h3;
      qq.x += h0 * h0; qq.y += h1 * h1; qq.z += h2 * h2; qq.w += h3 * h3;
    }
  }
  rs[ns][o4 * 4 + 0] = s.x;  rs[ns][o4 * 4 + 1] = s.y;
  rs[ns][o4 * 4 + 2] = s.z;  rs[ns][o4 * 4 + 3] = s.w;
  rq[ns][o4 * 4 + 0] = qq.x; rq[ns][o4 * 4 + 1] = qq.y;
  rq[ns][o4 * 4 + 2] = qq.z; rq[ns][o4 * 4 + 3] = qq.w;
  __syncthreads();
  if (tid < CO) {
    float ts = 0.f, tq = 0.f;
#pragma unroll
    for (int i = 0; i < 8; ++i) { ts += rs[i][tid]; tq += rq[i][tid]; }
    psums[(size_t)bid * CO + tid] = ts;
    psqs[(size_t)bid * CO + tid] = tq;
  }
}

// ---------------------------------------------------------------------------
// Kernel E: finalize BN stats -> scale/shift per channel.
// ---------------------------------------------------------------------------
__global__ void k_final(const float* __restrict__ psums,
                        const float* __restrict__ psqs,
                        const float* __restrict__ gamma,
                        const float* __restrict__ beta,
                        float* __restrict__ scale, float* __restrict__ shift) {
  int o = threadIdx.x;
  float s = 0.f, q = 0.f;
  for (int i = 0; i < BB * (NPT / 32); ++i) {
    s += psums[(size_t)i * CO + o];
    q += psqs[(size_t)i * CO + o];
  }
  const float M = (float)(BB * NPT * KK);
  float mean = s / M;
  float var = q / M - mean * mean;
  float sc = gamma[o] * rsqrtf(var + EPSV);
  scale[o] = sc;
  shift[o] = beta[o] - mean * sc;
}

// ---------------------------------------------------------------------------
// Kernel D: recompute h, normalize, max over k, write out (B, CO, N) via LDS
// transpose for coalesced stores.
// ---------------------------------------------------------------------------
__global__ __launch_bounds__(256) void k_out(
    const float* __restrict__ p, const float* __restrict__ v,
    const int* __restrict__ idx, const float* __restrict__ scale,
    const float* __restrict__ shift, float* __restrict__ out) {
  __shared__ float ob[32][132];   // row stride 528B (16B multiple)
  int bid = blockIdx.x;            // B * (N/32) = 512
  int b = bid >> 6;
  int n0 = (bid & 63) << 5;
  int tid = threadIdx.x;
  int o4 = tid & 31, ns = tid >> 5;
  float4 sc = *(const float4*)(scale + o4 * 4);
  float4 sh = *(const float4*)(shift + o4 * 4);
  const float* vb = v + (size_t)b * NPT * CO;
#pragma unroll 1
  for (int g = 0; g < 4; ++g) {
    int node = g * 8 + ns;
    int gn = b * NPT + n0 + node;
    float4 p4 = *(const float4*)(p + (size_t)gn * CO + o4 * 4);
    const int* id = idx + (size_t)gn * KK;
    float4 mx = {-3.4e38f, -3.4e38f, -3.4e38f, -3.4e38f};
#pragma unroll 1
    for (int k = 0; k < KK; ++k) {
      int j = id[k];
      float4 v4 = *(const float4*)(vb + (size_t)j * CO + o4 * 4);
      mx.x = fmaxf(mx.x, fmaxf(p4.x + v4.x, 0.f) * sc.x + sh.x);
      mx.y = fmaxf(mx.y, fmaxf(p4.y + v4.y, 0.f) * sc.y + sh.y);
      mx.z = fmaxf(mx.z, fmaxf(p4.z + v4.z, 0.f) * sc.z + sh.z);
      mx.w = fmaxf(mx.w, fmaxf(p4.w + v4.w, 0.f) * sc.w + sh.w);
    }
    *(float4*)&ob[node][o4 * 4] = mx;
  }
  __syncthreads();
  int ni = tid & 31, oh = tid >> 5;
#pragma unroll
  for (int pass = 0; pass < 16; ++pass) {
    int o = pass * 8 + oh;
    out[((size_t)(b * CO + o)) * NPT + n0 + ni] = ob[ni][o];
  }
}

// ---------------------------------------------------------------------------
extern "C" void kernel_launch(void* const* d_in, const int* in_sizes, int n_in,
                              void* d_out, int out_size, void* d_ws, size_t ws_size,
                              hipStream_t stream) {
  const float* x = (const float*)d_in[0];
  const float* W = (const float*)d_in[1];
  const float* bias = (const float*)d_in[2];
  const float* gamma = (const float*)d_in[3];
  const float* beta = (const float*)d_in[4];
  float* out = (float*)d_out;

  char* ws = (char*)d_ws;
  size_t off = 0;
  auto alloc = [&](size_t bytes) {
    void* ptr = ws + off;
    off += (bytes + 255) & ~(size_t)255;
    return ptr;
  };
  float* ft = (float*)alloc(sizeof(float) * BB * NPT * CIN);          // 4 MB
  float* sq = (float*)alloc(sizeof(float) * BB * NPT);                // 64 KB
  float* p = (float*)alloc(sizeof(float) * BB * NPT * CO);            // 8 MB
  float* v = (float*)alloc(sizeof(float) * BB * NPT * CO);            // 8 MB
  int* idx = (int*)alloc(sizeof(int) * BB * NPT * KK);                // 1 MB
  float* psums = (float*)alloc(sizeof(float) * BB * (NPT / 32) * CO); // 256 KB
  float* psqs = (float*)alloc(sizeof(float) * BB * (NPT / 32) * CO);  // 256 KB
  float* scale = (float*)alloc(sizeof(float) * CO);
  float* shift = (float*)alloc(sizeof(float) * CO);
  (void)ws_size; (void)in_sizes; (void)n_in; (void)out_size;

  hipLaunchKernelGGL(k_transpose_sq, dim3(BB * (NPT / 64)), dim3(256), 0, stream, x, ft, sq);
  hipLaunchKernelGGL(k_pv, dim3(BB * (NPT / 32)), dim3(256), 0, stream, ft, W, bias, p, v);
  hipLaunchKernelGGL(k_dist_topk, dim3(BB * (NPT / 8)), dim3(256), 0, stream, ft, sq, idx);
  hipLaunchKernelGGL(k_stats, dim3(BB * (NPT / 32)), dim3(256), 0, stream, p, v, idx, psums, psqs);
  hipLaunchKernelGGL(k_final, dim3(1), dim3(CO), 0, stream, psums, psqs, gamma, beta, scale, shift);
  hipLaunchKernelGGL(k_out, dim3(BB * (NPT / 32)), dim3(256), 0, stream, p, v, idx, scale, shift, out);
}

// Round 2
// 296.760 us; speedup vs baseline: 1.4645x; 1.4645x over previous
//
#include <hip/hip_runtime.h>
#include <math.h>

#define BB 8
#define CIN 64
#define CO 128
#define NPT 2048
#define KK 16
#define EPSV 1e-5f
#define LOSCALE 2048.0f   // lo-plane pre-scale: keeps f16 lo out of denormal range

typedef unsigned int u32;
typedef unsigned long long u64;
typedef _Float16 f16x8 __attribute__((ext_vector_type(8)));
typedef float f32x4 __attribute__((ext_vector_type(4)));

__device__ __forceinline__ u64 packdm(float f, int m) {
  // sortable-float key (monotonic in f) in high 32, (~m) low 32:
  // max() picks max value, ties break to lowest index (matches lax.top_k).
  u32 u = __float_as_uint(f);
  u = (u & 0x80000000u) ? ~u : (u | 0x80000000u);
  return ((u64)u << 32) | (u64)(0xFFFFFFFFu - (u32)m);
}

__device__ __forceinline__ u64 umax64(u64 a, u64 b) { return a > b ? a : b; }

__device__ __forceinline__ u64 shfl_xor_u64(u64 x, int mask) {
  int lo = __shfl_xor((int)(u32)x, mask, 64);
  int hi = __shfl_xor((int)(u32)(x >> 32), mask, 64);
  return ((u64)(u32)hi << 32) | (u64)(u32)lo;
}

// ---------------------------------------------------------------------------
// Kernel A: transpose x (B,C,N) -> ft (B,N,C) fp32, xh/xl f16 split planes,
// and sq[b][n] = sum_c x^2 (exact fp32).
//   x = hi + (lo / LOSCALE), hi = f16(x), lo = f16((x - hi) * LOSCALE)
// ---------------------------------------------------------------------------
__global__ __launch_bounds__(256) void k_prep(
    const float* __restrict__ x, float* __restrict__ ft, float* __restrict__ sq,
    _Float16* __restrict__ xh, _Float16* __restrict__ xl) {
  __shared__ float tile[64][65];
  __shared__ float psum[4][64];
  int bid = blockIdx.x;           // B * (N/64) = 256
  int b = bid >> 5;
  int n0 = (bid & 31) << 6;
  int tid = threadIdx.x;
  int q = tid >> 6, lo = tid & 63;
#pragma unroll
  for (int i = 0; i < 16; ++i) {
    int c = i * 4 + q;
    tile[c][lo] = x[((size_t)(b * CIN + c)) * NPT + n0 + lo];
  }
  __syncthreads();
  float ps = 0.f;
#pragma unroll
  for (int i = 0; i < 16; ++i) {
    float t = tile[q * 16 + i][lo];
    ps += t * t;
  }
  psum[q][lo] = ps;
#pragma unroll
  for (int i = 0; i < 16; ++i) {
    int ni = i * 4 + q;
    float val = tile[lo][ni];
    size_t o = ((size_t)(b * NPT + n0 + ni)) * CIN + lo;   // lanes vary lo -> coalesced
    ft[o] = val;
    _Float16 h = (_Float16)val;
    xh[o] = h;
    xl[o] = (_Float16)((val - (float)h) * LOSCALE);
  }
  __syncthreads();
  if (q == 0) {
    sq[(size_t)b * NPT + n0 + lo] = psum[0][lo] + psum[1][lo] + psum[2][lo] + psum[3][lo];
  }
}

// ---------------------------------------------------------------------------
// Kernel P: node-level matmuls p = (W1-W2)x + b, v = W2x  (h_edge = relu(p_i+v_j))
// ---------------------------------------------------------------------------
__global__ __launch_bounds__(256) void k_pv(
    const float* __restrict__ ft, const float* __restrict__ W,
    const float* __restrict__ bias, float* __restrict__ p, float* __restrict__ v) {
  __shared__ float xl[32][64];
  int bid = blockIdx.x;           // B * (N/32) = 512
  int b = bid >> 6;
  int n0 = (bid & 63) << 5;
  int tid = threadIdx.x;
  for (int i = tid; i < 32 * 64; i += 256) {
    xl[i >> 6][i & 63] = ft[((size_t)(b * NPT + n0 + (i >> 6))) * CIN + (i & 63)];
  }
  __syncthreads();
  int o = tid & 127, hh = tid >> 7;
  const float4* W1 = (const float4*)&W[o * 2 * CIN];
  const float4* W2 = (const float4*)&W[o * 2 * CIN + CIN];
  float bo = bias[o];
#pragma unroll 1
  for (int t = 0; t < 16; ++t) {
    int node = t * 2 + hh;
    float a1 = 0.f, a2 = 0.f;
#pragma unroll
    for (int c4 = 0; c4 < 16; ++c4) {
      float4 xv = *(const float4*)&xl[node][c4 * 4];
      float4 w1 = W1[c4];
      float4 w2 = W2[c4];
      a1 += xv.x * w1.x + xv.y * w1.y + xv.z * w1.z + xv.w * w1.w;
      a2 += xv.x * w2.x + xv.y * w2.y + xv.z * w2.z + xv.w * w2.w;
    }
    size_t gn = ((size_t)(b * NPT + n0 + node)) * CO + o;
    p[gn] = a1 - a2 + bo;
    v[gn] = a2;
  }
}

// ---------------------------------------------------------------------------
// Kernel B: 16 rows x 2048 cols per block. Phase 1: gram via f16 split-2 MFMA
// (hh + (hl+lh)/LOSCALE), pd = 2*gram - sq_i - sq_j into LDS. Phase 2: one
// wave per row, 32 candidates/lane in registers, 16x u64 butterfly extraction.
// ---------------------------------------------------------------------------
__global__ __launch_bounds__(1024) void k_dist_topk(
    const _Float16* __restrict__ xh, const _Float16* __restrict__ xl,
    const float* __restrict__ sq, int* __restrict__ idxout) {
  __shared__ float dist[16][NPT];   // 128 KiB (m201 precedent)
  int bid = blockIdx.x;             // B * (N/16) = 1024
  int b = bid >> 7;
  int rt = (bid & 127) << 4;        // row-tile base
  int tid = threadIdx.x;
  int w = tid >> 6, lane = tid & 63;
  int lr = lane & 15, lg = lane >> 4;   // fragment row/col index, k-group
  const _Float16* xhb = xh + (size_t)b * NPT * CIN;
  const _Float16* xlb = xl + (size_t)b * NPT * CIN;
  const float* sqb = sq + (size_t)b * NPT;

  // A fragments: rows rt..rt+15, k-chunks 0..31 / 32..63 (8 f16 = 16B per lane)
  const size_t arow = (size_t)(rt + lr) * CIN + lg * 8;
  f16x8 ah0 = *(const f16x8*)(xhb + arow);
  f16x8 ah1 = *(const f16x8*)(xhb + arow + 32);
  f16x8 al0 = *(const f16x8*)(xlb + arow);
  f16x8 al1 = *(const f16x8*)(xlb + arow + 32);
  float4 sqr = *(const float4*)(sqb + rt + lg * 4);

#pragma unroll 1
  for (int t = 0; t < 8; ++t) {
    int c = (w * 8 + t) * 16;
    const size_t brow = (size_t)(c + lr) * CIN + lg * 8;
    f16x8 bh0 = *(const f16x8*)(xhb + brow);
    f16x8 bh1 = *(const f16x8*)(xhb + brow + 32);
    f16x8 bl0 = *(const f16x8*)(xlb + brow);
    f16x8 bl1 = *(const f16x8*)(xlb + brow + 32);
    float sqc = sqb[c + lr];
    f32x4 acc0 = {0.f, 0.f, 0.f, 0.f};   // hi*hi
    f32x4 acc1 = {0.f, 0.f, 0.f, 0.f};   // (hi*lo + lo*hi) * LOSCALE
    acc1 = __builtin_amdgcn_mfma_f32_16x16x32_f16(ah0, bl0, acc1, 0, 0, 0);
    acc1 = __builtin_amdgcn_mfma_f32_16x16x32_f16(al0, bh0, acc1, 0, 0, 0);
    acc1 = __builtin_amdgcn_mfma_f32_16x16x32_f16(ah1, bl1, acc1, 0, 0, 0);
    acc1 = __builtin_amdgcn_mfma_f32_16x16x32_f16(al1, bh1, acc1, 0, 0, 0);
    acc0 = __builtin_amdgcn_mfma_f32_16x16x32_f16(ah0, bh0, acc0, 0, 0, 0);
    acc0 = __builtin_amdgcn_mfma_f32_16x16x32_f16(ah1, bh1, acc0, 0, 0, 0);
    // D mapping (m89-verified, dtype-independent): col=lane&15, row=lg*4+reg
    const float k2 = 2.0f / LOSCALE;
    dist[lg * 4 + 0][c + lr] = fmaf(acc1[0], k2, 2.f * acc0[0]) - (sqr.x + sqc);
    dist[lg * 4 + 1][c + lr] = fmaf(acc1[1], k2, 2.f * acc0[1]) - (sqr.y + sqc);
    dist[lg * 4 + 2][c + lr] = fmaf(acc1[2], k2, 2.f * acc0[2]) - (sqr.z + sqc);
    dist[lg * 4 + 3][c + lr] = fmaf(acc1[3], k2, 2.f * acc0[3]) - (sqr.w + sqc);
  }
  __syncthreads();

  // Phase 2: wave w owns row w; lane owns cols lane, lane+64, ... (32 regs).
  float vals[32];
#pragma unroll
  for (int i = 0; i < 32; ++i) vals[i] = dist[w][i * 64 + lane];
  u64 best = 0;
#pragma unroll
  for (int i = 0; i < 32; ++i) best = umax64(best, packdm(vals[i], i * 64 + lane));
  int* myidx = idxout + ((size_t)(b * NPT + rt + w)) * KK;
#pragma unroll 1
  for (int it = 0; it < KK; ++it) {
    u64 vv = best;
#pragma unroll
    for (int s = 1; s < 64; s <<= 1) vv = umax64(vv, shfl_xor_u64(vv, s));
    int mwin = (int)(0xFFFFFFFFu - (u32)vv);
    if (lane == (mwin & 63)) {
      int slot = mwin >> 6;
      u64 nb = 0;
#pragma unroll
      for (int i = 0; i < 32; ++i) {     // static indexing: stays in VGPRs
        float f = (i == slot) ? -__builtin_inff() : vals[i];
        vals[i] = f;
        nb = umax64(nb, packdm(f, i * 64 + lane));
      }
      best = nb;
    }
    if (lane == 0) myidx[it] = mwin;
  }
}

// ---------------------------------------------------------------------------
// Kernel C: per-block partial sums of h, h^2 per channel + per-(node,ch)
// max/min of h.  mn is written IN PLACE over p (each element read once by the
// same thread that overwrites it); mx goes to the dead ft/xh/xl region.
// ---------------------------------------------------------------------------
__global__ __launch_bounds__(256) void k_stats(
    float* p_mn, const float* __restrict__ v, const int* __restrict__ idx,
    float* __restrict__ psums, float* __restrict__ psqs, float* __restrict__ mxb) {
  __shared__ float rs[8][CO];
  __shared__ float rq[8][CO];
  int bid = blockIdx.x;            // B * (N/32) = 512
  int b = bid >> 6;
  int n0 = (bid & 63) << 5;
  int tid = threadIdx.x;
  int o4 = tid & 31, ns = tid >> 5;
  const float* vb = v + (size_t)b * NPT * CO;
  float4 s = {0.f, 0.f, 0.f, 0.f};
  float4 qq = {0.f, 0.f, 0.f, 0.f};
#pragma unroll 1
  for (int g = 0; g < 4; ++g) {
    int gn = b * NPT + n0 + g * 8 + ns;
    size_t po = (size_t)gn * CO + o4 * 4;
    float4 p4 = *(const float4*)(p_mn + po);
    const int* id = idx + (size_t)gn * KK;
    float4 mx4 = {-1e30f, -1e30f, -1e30f, -1e30f};
    float4 mn4 = {1e30f, 1e30f, 1e30f, 1e30f};
#pragma unroll 1
    for (int k = 0; k < KK; ++k) {
      int j = id[k];
      float4 v4 = *(const float4*)(vb + (size_t)j * CO + o4 * 4);
      float h0 = fmaxf(p4.x + v4.x, 0.f);
      float h1 = fmaxf(p4.y + v4.y, 0.f);
      float h2 = fmaxf(p4.z + v4.z, 0.f);
      float h3 = fmaxf(p4.w + v4.w, 0.f);
      s.x += h0; s.y += h1; s.z += h2; s.w += h3;
      qq.x += h0 * h0; qq.y += h1 * h1; qq.z += h2 * h2; qq.w += h3 * h3;
      mx4.x = fmaxf(mx4.x, h0); mx4.y = fmaxf(mx4.y, h1);
      mx4.z = fmaxf(mx4.z, h2); mx4.w = fmaxf(mx4.w, h3);
      mn4.x = fminf(mn4.x, h0); mn4.y = fminf(mn4.y, h1);
      mn4.z = fminf(mn4.z, h2); mn4.w = fminf(mn4.w, h3);
    }
    *(float4*)(mxb + po) = mx4;
    *(float4*)(p_mn + po) = mn4;   // p element already consumed by this thread
  }
  rs[ns][o4 * 4 + 0] = s.x;  rs[ns][o4 * 4 + 1] = s.y;
  rs[ns][o4 * 4 + 2] = s.z;  rs[ns][o4 * 4 + 3] = s.w;
  rq[ns][o4 * 4 + 0] = qq.x; rq[ns][o4 * 4 + 1] = qq.y;
  rq[ns][o4 * 4 + 2] = qq.z; rq[ns][o4 * 4 + 3] = qq.w;
  __syncthreads();
  if (tid < CO) {
    float ts = 0.f, tq = 0.f;
#pragma unroll
    for (int i = 0; i < 8; ++i) { ts += rs[i][tid]; tq += rq[i][tid]; }
    psums[(size_t)bid * CO + tid] = ts;
    psqs[(size_t)bid * CO + tid] = tq;
  }
}

// ---------------------------------------------------------------------------
// Kernel E: finalize BN stats -> scale/shift. One block per channel.
// ---------------------------------------------------------------------------
__global__ __launch_bounds__(64) void k_final(
    const float* __restrict__ psums, const float* __restrict__ psqs,
    const float* __restrict__ gamma, const float* __restrict__ beta,
    float* __restrict__ scale, float* __restrict__ shift) {
  int o = blockIdx.x;   // 0..127
  int t = threadIdx.x;  // 0..63
  float s = 0.f, q = 0.f;
  for (int i = t; i < BB * (NPT / 32); i += 64) {
    s += psums[(size_t)i * CO + o];
    q += psqs[(size_t)i * CO + o];
  }
#pragma unroll
  for (int d = 32; d >= 1; d >>= 1) {
    s += __shfl_down(s, d, 64);
    q += __shfl_down(q, d, 64);
  }
  if (t == 0) {
    const float M = (float)(BB * NPT * KK);
    float mean = s / M;
    float var = q / M - mean * mean;
    float sc = gamma[o] * rsqrtf(var + EPSV);
    scale[o] = sc;
    shift[o] = beta[o] - mean * sc;
  }
}

// ---------------------------------------------------------------------------
// Kernel D: out = (sc>=0 ? mx : mn)*sc + sh  (relu monotone => max_k commutes
// with the affine map), transpose-write (B, CO, N). No gathers.
// ---------------------------------------------------------------------------
__global__ __launch_bounds__(256) void k_out_fast(
    const float* __restrict__ mxb, const float* __restrict__ mnb,
    const float* __restrict__ scale, const float* __restrict__ shift,
    float* __restrict__ out) {
  __shared__ float ob[32][132];
  int bid = blockIdx.x;            // B * (N/32) = 512
  int b = bid >> 6;
  int n0 = (bid & 63) << 5;
  int tid = threadIdx.x;
  int o4 = tid & 31, ns = tid >> 5;
  float4 sc = *(const float4*)(scale + o4 * 4);
  float4 sh = *(const float4*)(shift + o4 * 4);
#pragma unroll
  for (int g = 0; g < 4; ++g) {
    int node = g * 8 + ns;
    size_t po = (size_t)(b * NPT + n0 + node) * CO + o4 * 4;
    float4 mx = *(const float4*)(mxb + po);
    float4 mn = *(const float4*)(mnb + po);
    float4 r;
    r.x = (sc.x >= 0.f ? mx.x : mn.x) * sc.x + sh.x;
    r.y = (sc.y >= 0.f ? mx.y : mn.y) * sc.y + sh.y;
    r.z = (sc.z >= 0.f ? mx.z : mn.z) * sc.z + sh.z;
    r.w = (sc.w >= 0.f ? mx.w : mn.w) * sc.w + sh.w;
    *(float4*)&ob[node][o4 * 4] = r;
  }
  __syncthreads();
  int ni = tid & 31, oh = tid >> 5;
#pragma unroll
  for (int pass = 0; pass < 16; ++pass) {
    int o = pass * 8 + oh;
    out[((size_t)(b * CO + o)) * NPT + n0 + ni] = ob[ni][o];
  }
}

// ---------------------------------------------------------------------------
extern "C" void kernel_launch(void* const* d_in, const int* in_sizes, int n_in,
                              void* d_out, int out_size, void* d_ws, size_t ws_size,
                              hipStream_t stream) {
  const float* x = (const float*)d_in[0];
  const float* W = (const float*)d_in[1];
  const float* bias = (const float*)d_in[2];
  const float* gamma = (const float*)d_in[3];
  const float* beta = (const float*)d_in[4];
  float* out = (float*)d_out;

  char* ws = (char*)d_ws;
  size_t off = 0;
  auto alloc = [&](size_t bytes) {
    void* ptr = ws + off;
    off += (bytes + 255) & ~(size_t)255;
    return ptr;
  };
  // ft+xh+xl laid out contiguously = exactly 8 MB; dead after k_dist_topk,
  // reused as mx by k_stats.
  float* ft = (float*)alloc(sizeof(float) * BB * NPT * CIN);            // 4 MB
  _Float16* xh = (_Float16*)alloc(sizeof(_Float16) * BB * NPT * CIN);   // 2 MB
  _Float16* xl = (_Float16*)alloc(sizeof(_Float16) * BB * NPT * CIN);   // 2 MB
  float* mx = ft;                                                        // alias
  float* sq = (float*)alloc(sizeof(float) * BB * NPT);                  // 64 KB
  float* p = (float*)alloc(sizeof(float) * BB * NPT * CO);              // 8 MB (becomes mn)
  float* v = (float*)alloc(sizeof(float) * BB * NPT * CO);              // 8 MB
  int* idx = (int*)alloc(sizeof(int) * BB * NPT * KK);                  // 1 MB
  float* psums = (float*)alloc(sizeof(float) * BB * (NPT / 32) * CO);   // 256 KB
  float* psqs = (float*)alloc(sizeof(float) * BB * (NPT / 32) * CO);    // 256 KB
  float* scale = (float*)alloc(sizeof(float) * CO);
  float* shift = (float*)alloc(sizeof(float) * CO);
  (void)ws_size; (void)in_sizes; (void)n_in; (void)out_size;

  hipLaunchKernelGGL(k_prep, dim3(BB * (NPT / 64)), dim3(256), 0, stream, x, ft, sq, xh, xl);
  hipLaunchKernelGGL(k_pv, dim3(BB * (NPT / 32)), dim3(256), 0, stream, ft, W, bias, p, v);
  hipLaunchKernelGGL(k_dist_topk, dim3(BB * (NPT / 16)), dim3(1024), 0, stream, xh, xl, sq, idx);
  hipLaunchKernelGGL(k_stats, dim3(BB * (NPT / 32)), dim3(256), 0, stream, p, v, idx, psums, psqs, mx);
  hipLaunchKernelGGL(k_final, dim3(CO), dim3(64), 0, stream, psums, psqs, gamma, beta, scale, shift);
  hipLaunchKernelGGL(k_out_fast, dim3(BB * (NPT / 32)), dim3(256), 0, stream, mx, p, scale, shift, out);
}

// Round 3
// 231.159 us; speedup vs baseline: 1.8801x; 1.2838x over previous
//
#include <hip/hip_runtime.h>
#include <math.h>

#define BB 8
#define CIN 64
#define CO 128
#define NPT 2048
#define KK 16
#define EPSV 1e-5f
#define LOSCALE 2048.0f   // lo-plane pre-scale: keeps f16 lo out of denormal range

typedef unsigned int u32;
typedef unsigned long long u64;
typedef _Float16 f16x8 __attribute__((ext_vector_type(8)));
typedef float f32x4 __attribute__((ext_vector_type(4)));

__device__ __forceinline__ u64 packdm(float f, int m) {
  // sortable-float key (monotonic in f) in high 32, (~m) low 32:
  // max() picks max value, ties break to lowest index (matches lax.top_k).
  u32 u = __float_as_uint(f);
  u = (u & 0x80000000u) ? ~u : (u | 0x80000000u);
  return ((u64)u << 32) | (u64)(0xFFFFFFFFu - (u32)m);
}

__device__ __forceinline__ u64 umax64(u64 a, u64 b) { return a > b ? a : b; }

__device__ __forceinline__ u64 shfl_xor_u64(u64 x, int mask) {
  int lo = __shfl_xor((int)(u32)x, mask, 64);
  int hi = __shfl_xor((int)(u32)(x >> 32), mask, 64);
  return ((u64)(u32)hi << 32) | (u64)(u32)lo;
}

// ---------------------------------------------------------------------------
// Kernel A: transpose x (B,C,N) -> ft (B,N,C) fp32, xh/xl f16 split planes,
// and sq[b][n] = sum_c x^2 (exact fp32).
// ---------------------------------------------------------------------------
__global__ __launch_bounds__(256) void k_prep(
    const float* __restrict__ x, float* __restrict__ ft, float* __restrict__ sq,
    _Float16* __restrict__ xh, _Float16* __restrict__ xl) {
  __shared__ float tile[64][65];
  __shared__ float psum[4][64];
  int bid = blockIdx.x;           // B * (N/64) = 256
  int b = bid >> 5;
  int n0 = (bid & 31) << 6;
  int tid = threadIdx.x;
  int q = tid >> 6, lo = tid & 63;
#pragma unroll
  for (int i = 0; i < 16; ++i) {
    int c = i * 4 + q;
    tile[c][lo] = x[((size_t)(b * CIN + c)) * NPT + n0 + lo];
  }
  __syncthreads();
  float ps = 0.f;
#pragma unroll
  for (int i = 0; i < 16; ++i) {
    float t = tile[q * 16 + i][lo];
    ps += t * t;
  }
  psum[q][lo] = ps;
#pragma unroll
  for (int i = 0; i < 16; ++i) {
    int ni = i * 4 + q;
    float val = tile[lo][ni];
    size_t o = ((size_t)(b * NPT + n0 + ni)) * CIN + lo;
    ft[o] = val;
    _Float16 h = (_Float16)val;
    xh[o] = h;
    xl[o] = (_Float16)((val - (float)h) * LOSCALE);
  }
  __syncthreads();
  if (q == 0) {
    sq[(size_t)b * NPT + n0 + lo] = psum[0][lo] + psum[1][lo] + psum[2][lo] + psum[3][lo];
  }
}

// ---------------------------------------------------------------------------
// Kernel P: node-level matmuls p = (W1-W2)x + b, v = W2x  (h_edge = relu(p_i+v_j))
// ---------------------------------------------------------------------------
__global__ __launch_bounds__(256) void k_pv(
    const float* __restrict__ ft, const float* __restrict__ W,
    const float* __restrict__ bias, float* __restrict__ p, float* __restrict__ v) {
  __shared__ float xl[32][64];
  int bid = blockIdx.x;           // B * (N/32) = 512
  int b = bid >> 6;
  int n0 = (bid & 63) << 5;
  int tid = threadIdx.x;
  for (int i = tid; i < 32 * 64; i += 256) {
    xl[i >> 6][i & 63] = ft[((size_t)(b * NPT + n0 + (i >> 6))) * CIN + (i & 63)];
  }
  __syncthreads();
  int o = tid & 127, hh = tid >> 7;
  const float4* W1 = (const float4*)&W[o * 2 * CIN];
  const float4* W2 = (const float4*)&W[o * 2 * CIN + CIN];
  float bo = bias[o];
#pragma unroll 1
  for (int t = 0; t < 16; ++t) {
    int node = t * 2 + hh;
    float a1 = 0.f, a2 = 0.f;
#pragma unroll
    for (int c4 = 0; c4 < 16; ++c4) {
      float4 xv = *(const float4*)&xl[node][c4 * 4];
      float4 w1 = W1[c4];
      float4 w2 = W2[c4];
      a1 += xv.x * w1.x + xv.y * w1.y + xv.z * w1.z + xv.w * w1.w;
      a2 += xv.x * w2.x + xv.y * w2.y + xv.z * w2.z + xv.w * w2.w;
    }
    size_t gn = ((size_t)(b * NPT + n0 + node)) * CO + o;
    p[gn] = a1 - a2 + bo;
    v[gn] = a2;
  }
}

// ---------------------------------------------------------------------------
// Kernel B: 16 rows x 2048 cols per block.
// Phase 1: gram via f16 split-2 MFMA, pd = 2*gram - sq_i - sq_j into LDS with
//   XOR swizzle  sw(m,r) = m ^ ((m>>6)&31) ^ (((r>>2)&1)<<4)
//   (conflict-free for both phase-2 access patterns; 2-way on stores = free).
// Phase 2: one wave per row; lane owns m = i*64+lane. 16 rounds of u64
//   butterfly-max; winner's per-lane best recomputed by a 32-lane PARALLEL
//   re-reduce of its LDS column set (replaces the serial 32-slot rescan).
// ---------------------------------------------------------------------------
__global__ __launch_bounds__(1024) void k_dist_topk(
    const _Float16* __restrict__ xh, const _Float16* __restrict__ xl,
    const float* __restrict__ sq, int* __restrict__ idxout) {
  __shared__ float dist[16][NPT];   // 128 KiB
  int bid = blockIdx.x;             // B * (N/16) = 1024
  int b = bid >> 7;
  int rt = (bid & 127) << 4;        // row-tile base
  int tid = threadIdx.x;
  int w = tid >> 6, lane = tid & 63;
  int lr = lane & 15, lg = lane >> 4;   // fragment row index, k-group
  const _Float16* xhb = xh + (size_t)b * NPT * CIN;
  const _Float16* xlb = xl + (size_t)b * NPT * CIN;
  const float* sqb = sq + (size_t)b * NPT;

  // A fragments: rows rt..rt+15, k-chunks 0..31 / 32..63
  const size_t arow = (size_t)(rt + lr) * CIN + lg * 8;
  f16x8 ah0 = *(const f16x8*)(xhb + arow);
  f16x8 ah1 = *(const f16x8*)(xhb + arow + 32);
  f16x8 al0 = *(const f16x8*)(xlb + arow);
  f16x8 al1 = *(const f16x8*)(xlb + arow + 32);
  float4 sqr = *(const float4*)(sqb + rt + lg * 4);
  float sqrv[4] = {sqr.x, sqr.y, sqr.z, sqr.w};

#pragma unroll 1
  for (int t = 0; t < 8; ++t) {
    int c = (w * 8 + t) * 16;
    const size_t brow = (size_t)(c + lr) * CIN + lg * 8;
    f16x8 bh0 = *(const f16x8*)(xhb + brow);
    f16x8 bh1 = *(const f16x8*)(xhb + brow + 32);
    f16x8 bl0 = *(const f16x8*)(xlb + brow);
    f16x8 bl1 = *(const f16x8*)(xlb + brow + 32);
    float sqc = sqb[c + lr];
    f32x4 acc0 = {0.f, 0.f, 0.f, 0.f};   // hi*hi
    f32x4 acc1 = {0.f, 0.f, 0.f, 0.f};   // (hi*lo + lo*hi) * LOSCALE
    acc1 = __builtin_amdgcn_mfma_f32_16x16x32_f16(ah0, bl0, acc1, 0, 0, 0);
    acc1 = __builtin_amdgcn_mfma_f32_16x16x32_f16(al0, bh0, acc1, 0, 0, 0);
    acc1 = __builtin_amdgcn_mfma_f32_16x16x32_f16(ah1, bl1, acc1, 0, 0, 0);
    acc1 = __builtin_amdgcn_mfma_f32_16x16x32_f16(al1, bh1, acc1, 0, 0, 0);
    acc0 = __builtin_amdgcn_mfma_f32_16x16x32_f16(ah0, bh0, acc0, 0, 0, 0);
    acc0 = __builtin_amdgcn_mfma_f32_16x16x32_f16(ah1, bh1, acc0, 0, 0, 0);
    // D mapping (m89-verified): col = lane&15, row = lg*4 + reg
    const float k2 = 2.0f / LOSCALE;
    int colm = c + lr;
    int msw = colm ^ ((colm >> 6) & 31);   // (colm>>6) constant across the 16-lane group
#pragma unroll
    for (int q = 0; q < 4; ++q) {
      int r = lg * 4 + q;
      int sw = msw ^ (((r >> 2) & 1) << 4);
      dist[r][sw] = fmaf(acc1[q], k2, 2.f * acc0[q]) - (sqrv[q] + sqc);
    }
  }
  __syncthreads();

  // Phase 2: wave w owns row w; lane owns m = i*64 + lane (i = 0..31).
  const int rxor = ((w >> 2) & 1) << 4;
  float bf = -__builtin_inff();
  int bi = 0;
#pragma unroll
  for (int i = 0; i < 32; ++i) {
    int m = i * 64 + lane;                 // m>>6 == i
    float f = dist[w][m ^ i ^ rxor];
    if (f > bf) { bf = f; bi = m; }        // strict > : ties keep lowest m
  }
  u64 best = packdm(bf, bi);
  int* myidx = idxout + ((size_t)(b * NPT + rt + w)) * KK;
#pragma unroll 1
  for (int it = 0; it < KK; ++it) {
    u64 vv = best;
#pragma unroll
    for (int s = 1; s < 64; s <<= 1) vv = umax64(vv, shfl_xor_u64(vv, s));
    int mwin = (int)(0xFFFFFFFFu - (u32)vv);
    if (lane == 0) {
      int swin = mwin ^ ((mwin >> 6) & 31) ^ rxor;
      dist[w][swin] = -__builtin_inff();
    }
    asm volatile("s_waitcnt lgkmcnt(0)" ::: "memory");
    // parallel recompute of winner lane's best (its candidates: m ≡ cw mod 64)
    int cw = mwin & 63;
    int j = lane & 31;
    int m2 = j * 64 + cw;                  // m2>>6 == j
    float f2 = dist[w][m2 ^ j ^ rxor];
    u64 nb = packdm(f2, m2);
#pragma unroll
    for (int s = 1; s < 32; s <<= 1) nb = umax64(nb, shfl_xor_u64(nb, s));
    if (lane == cw) best = nb;
    if (lane == 0) myidx[it] = mwin;
  }
}

// ---------------------------------------------------------------------------
// Kernel C: per-block partial sums of h, h^2 per channel + per-(node,ch)
// max/min of h.  mn overwrites p in place; mx goes to the dead ft/xh/xl region.
// ---------------------------------------------------------------------------
__global__ __launch_bounds__(256) void k_stats(
    float* p_mn, const float* __restrict__ v, const int* __restrict__ idx,
    float* __restrict__ psums, float* __restrict__ psqs, float* __restrict__ mxb) {
  __shared__ float rs[8][CO];
  __shared__ float rq[8][CO];
  int bid = blockIdx.x;            // B * (N/32) = 512
  int b = bid >> 6;
  int n0 = (bid & 63) << 5;
  int tid = threadIdx.x;
  int o4 = tid & 31, ns = tid >> 5;
  const float* vb = v + (size_t)b * NPT * CO;
  float4 s = {0.f, 0.f, 0.f, 0.f};
  float4 qq = {0.f, 0.f, 0.f, 0.f};
#pragma unroll 1
  for (int g = 0; g < 4; ++g) {
    int gn = b * NPT + n0 + g * 8 + ns;
    size_t po = (size_t)gn * CO + o4 * 4;
    float4 p4 = *(const float4*)(p_mn + po);
    const int* id = idx + (size_t)gn * KK;
    float4 mx4 = {-1e30f, -1e30f, -1e30f, -1e30f};
    float4 mn4 = {1e30f, 1e30f, 1e30f, 1e30f};
#pragma unroll 1
    for (int k = 0; k < KK; ++k) {
      int j = id[k];
      float4 v4 = *(const float4*)(vb + (size_t)j * CO + o4 * 4);
      float h0 = fmaxf(p4.x + v4.x, 0.f);
      float h1 = fmaxf(p4.y + v4.y, 0.f);
      float h2 = fmaxf(p4.z + v4.z, 0.f);
      float h3 = fmaxf(p4.w + v4.w, 0.f);
      s.x += h0; s.y += h1; s.z += h2; s.w += h3;
      qq.x += h0 * h0; qq.y += h1 * h1; qq.z += h2 * h2; qq.w += h3 * h3;
      mx4.x = fmaxf(mx4.x, h0); mx4.y = fmaxf(mx4.y, h1);
      mx4.z = fmaxf(mx4.z, h2); mx4.w = fmaxf(mx4.w, h3);
      mn4.x = fminf(mn4.x, h0); mn4.y = fminf(mn4.y, h1);
      mn4.z = fminf(mn4.z, h2); mn4.w = fminf(mn4.w, h3);
    }
    *(float4*)(mxb + po) = mx4;
    *(float4*)(p_mn + po) = mn4;
  }
  rs[ns][o4 * 4 + 0] = s.x;  rs[ns][o4 * 4 + 1] = s.y;
  rs[ns][o4 * 4 + 2] = s.z;  rs[ns][o4 * 4 + 3] = s.w;
  rq[ns][o4 * 4 + 0] = qq.x; rq[ns][o4 * 4 + 1] = qq.y;
  rq[ns][o4 * 4 + 2] = qq.z; rq[ns][o4 * 4 + 3] = qq.w;
  __syncthreads();
  if (tid < CO) {
    float ts = 0.f, tq = 0.f;
#pragma unroll
    for (int i = 0; i < 8; ++i) { ts += rs[i][tid]; tq += rq[i][tid]; }
    psums[(size_t)bid * CO + tid] = ts;
    psqs[(size_t)bid * CO + tid] = tq;
  }
}

// ---------------------------------------------------------------------------
// Kernel E: finalize BN stats -> scale/shift. One block per channel.
// ---------------------------------------------------------------------------
__global__ __launch_bounds__(64) void k_final(
    const float* __restrict__ psums, const float* __restrict__ psqs,
    const float* __restrict__ gamma, const float* __restrict__ beta,
    float* __restrict__ scale, float* __restrict__ shift) {
  int o = blockIdx.x;   // 0..127
  int t = threadIdx.x;  // 0..63
  float s = 0.f, q = 0.f;
  for (int i = t; i < BB * (NPT / 32); i += 64) {
    s += psums[(size_t)i * CO + o];
    q += psqs[(size_t)i * CO + o];
  }
#pragma unroll
  for (int d = 32; d >= 1; d >>= 1) {
    s += __shfl_down(s, d, 64);
    q += __shfl_down(q, d, 64);
  }
  if (t == 0) {
    const float M = (float)(BB * NPT * KK);
    float mean = s / M;
    float var = q / M - mean * mean;
    float sc = gamma[o] * rsqrtf(var + EPSV);
    scale[o] = sc;
    shift[o] = beta[o] - mean * sc;
  }
}

// ---------------------------------------------------------------------------
// Kernel D: out = (sc>=0 ? mx : mn)*sc + sh, transpose-write (B, CO, N).
// ---------------------------------------------------------------------------
__global__ __launch_bounds__(256) void k_out_fast(
    const float* __restrict__ mxb, const float* __restrict__ mnb,
    const float* __restrict__ scale, const float* __restrict__ shift,
    float* __restrict__ out) {
  __shared__ float ob[32][132];
  int bid = blockIdx.x;            // B * (N/32) = 512
  int b = bid >> 6;
  int n0 = (bid & 63) << 5;
  int tid = threadIdx.x;
  int o4 = tid & 31, ns = tid >> 5;
  float4 sc = *(const float4*)(scale + o4 * 4);
  float4 sh = *(const float4*)(shift + o4 * 4);
#pragma unroll
  for (int g = 0; g < 4; ++g) {
    int node = g * 8 + ns;
    size_t po = (size_t)(b * NPT + n0 + node) * CO + o4 * 4;
    float4 mx = *(const float4*)(mxb + po);
    float4 mn = *(const float4*)(mnb + po);
    float4 r;
    r.x = (sc.x >= 0.f ? mx.x : mn.x) * sc.x + sh.x;
    r.y = (sc.y >= 0.f ? mx.y : mn.y) * sc.y + sh.y;
    r.z = (sc.z >= 0.f ? mx.z : mn.z) * sc.z + sh.z;
    r.w = (sc.w >= 0.f ? mx.w : mn.w) * sc.w + sh.w;
    *(float4*)&ob[node][o4 * 4] = r;
  }
  __syncthreads();
  int ni = tid & 31, oh = tid >> 5;
#pragma unroll
  for (int pass = 0; pass < 16; ++pass) {
    int o = pass * 8 + oh;
    out[((size_t)(b * CO + o)) * NPT + n0 + ni] = ob[ni][o];
  }
}

// ---------------------------------------------------------------------------
extern "C" void kernel_launch(void* const* d_in, const int* in_sizes, int n_in,
                              void* d_out, int out_size, void* d_ws, size_t ws_size,
                              hipStream_t stream) {
  const float* x = (const float*)d_in[0];
  const float* W = (const float*)d_in[1];
  const float* bias = (const float*)d_in[2];
  const float* gamma = (const float*)d_in[3];
  const float* beta = (const float*)d_in[4];
  float* out = (float*)d_out;

  char* ws = (char*)d_ws;
  size_t off = 0;
  auto alloc = [&](size_t bytes) {
    void* ptr = ws + off;
    off += (bytes + 255) & ~(size_t)255;
    return ptr;
  };
  float* ft = (float*)alloc(sizeof(float) * BB * NPT * CIN);            // 4 MB
  _Float16* xh = (_Float16*)alloc(sizeof(_Float16) * BB * NPT * CIN);   // 2 MB
  _Float16* xl = (_Float16*)alloc(sizeof(_Float16) * BB * NPT * CIN);   // 2 MB
  float* mx = ft;                                                        // alias (dead after k_dist_topk)
  float* sq = (float*)alloc(sizeof(float) * BB * NPT);                  // 64 KB
  float* p = (float*)alloc(sizeof(float) * BB * NPT * CO);              // 8 MB (becomes mn)
  float* v = (float*)alloc(sizeof(float) * BB * NPT * CO);              // 8 MB
  int* idx = (int*)alloc(sizeof(int) * BB * NPT * KK);                  // 1 MB
  float* psums = (float*)alloc(sizeof(float) * BB * (NPT / 32) * CO);   // 256 KB
  float* psqs = (float*)alloc(sizeof(float) * BB * (NPT / 32) * CO);    // 256 KB
  float* scale = (float*)alloc(sizeof(float) * CO);
  float* shift = (float*)alloc(sizeof(float) * CO);
  (void)ws_size; (void)in_sizes; (void)n_in; (void)out_size;

  hipLaunchKernelGGL(k_prep, dim3(BB * (NPT / 64)), dim3(256), 0, stream, x, ft, sq, xh, xl);
  hipLaunchKernelGGL(k_pv, dim3(BB * (NPT / 32)), dim3(256), 0, stream, ft, W, bias, p, v);
  hipLaunchKernelGGL(k_dist_topk, dim3(BB * (NPT / 16)), dim3(1024), 0, stream, xh, xl, sq, idx);
  hipLaunchKernelGGL(k_stats, dim3(BB * (NPT / 32)), dim3(256), 0, stream, p, v, idx, psums, psqs, mx);
  hipLaunchKernelGGL(k_final, dim3(CO), dim3(64), 0, stream, psums, psqs, gamma, beta, scale, shift);
  hipLaunchKernelGGL(k_out_fast, dim3(BB * (NPT / 32)), dim3(256), 0, stream, mx, p, scale, shift, out);
}

// Round 4
// 183.985 us; speedup vs baseline: 2.3621x; 1.2564x over previous
//
#include <hip/hip_runtime.h>
#include <math.h>

#define BB 8
#define CIN 64
#define CO 128
#define NPT 2048
#define KK 16
#define EPSV 1e-5f
#define LOSCALE 2048.0f   // lo-plane pre-scale: keeps f16 lo out of denormal range

typedef unsigned int u32;
typedef unsigned long long u64;
typedef _Float16 f16x8 __attribute__((ext_vector_type(8)));
typedef float f32x4 __attribute__((ext_vector_type(4)));

__device__ __forceinline__ u64 packdm(float f, int m) {
  // sortable-float key (monotonic in f) in high 32, (~m) low 32:
  // max() picks max value, ties break to lowest index (matches lax.top_k).
  // Never returns 0 for m in [0,2048): low32 >= 0xFFFFF800.
  u32 u = __float_as_uint(f);
  u = (u & 0x80000000u) ? ~u : (u | 0x80000000u);
  return ((u64)u << 32) | (u64)(0xFFFFFFFFu - (u32)m);
}

__device__ __forceinline__ u64 umax64(u64 a, u64 b) { return a > b ? a : b; }

__device__ __forceinline__ u64 shfl_xor_u64(u64 x, int mask) {
  int lo = __shfl_xor((int)(u32)x, mask, 64);
  int hi = __shfl_xor((int)(u32)(x >> 32), mask, 64);
  return ((u64)(u32)hi << 32) | (u64)(u32)lo;
}
__device__ __forceinline__ u64 shfl_u64(u64 x, int src) {
  int lo = __shfl((int)(u32)x, src, 64);
  int hi = __shfl((int)(u32)(x >> 32), src, 64);
  return ((u64)(u32)hi << 32) | (u64)(u32)lo;
}
__device__ __forceinline__ u64 shfl_down_u64(u64 x, int d) {
  int lo = __shfl_down((int)(u32)x, d, 64);
  int hi = __shfl_down((int)(u32)(x >> 32), d, 64);
  return ((u64)(u32)hi << 32) | (u64)(u32)lo;
}

// ---------------------------------------------------------------------------
// Kernel A: transpose x (B,C,N) -> ft (B,N,C) fp32, xh/xl f16 split planes,
// and sq[b][n] = sum_c x^2 (exact fp32).
// ---------------------------------------------------------------------------
__global__ __launch_bounds__(256) void k_prep(
    const float* __restrict__ x, float* __restrict__ ft, float* __restrict__ sq,
    _Float16* __restrict__ xh, _Float16* __restrict__ xl) {
  __shared__ float tile[64][65];
  __shared__ float psum[4][64];
  int bid = blockIdx.x;           // B * (N/64) = 256
  int b = bid >> 5;
  int n0 = (bid & 31) << 6;
  int tid = threadIdx.x;
  int q = tid >> 6, lo = tid & 63;
#pragma unroll
  for (int i = 0; i < 16; ++i) {
    int c = i * 4 + q;
    tile[c][lo] = x[((size_t)(b * CIN + c)) * NPT + n0 + lo];
  }
  __syncthreads();
  float ps = 0.f;
#pragma unroll
  for (int i = 0; i < 16; ++i) {
    float t = tile[q * 16 + i][lo];
    ps += t * t;
  }
  psum[q][lo] = ps;
#pragma unroll
  for (int i = 0; i < 16; ++i) {
    int ni = i * 4 + q;
    float val = tile[lo][ni];
    size_t o = ((size_t)(b * NPT + n0 + ni)) * CIN + lo;
    ft[o] = val;
    _Float16 h = (_Float16)val;
    xh[o] = h;
    xl[o] = (_Float16)((val - (float)h) * LOSCALE);
  }
  __syncthreads();
  if (q == 0) {
    sq[(size_t)b * NPT + n0 + lo] = psum[0][lo] + psum[1][lo] + psum[2][lo] + psum[3][lo];
  }
}

// ---------------------------------------------------------------------------
// Kernel P: node-level matmuls p = (W1-W2)x + b, v = W2x  (h_edge = relu(p_i+v_j))
// ---------------------------------------------------------------------------
__global__ __launch_bounds__(256) void k_pv(
    const float* __restrict__ ft, const float* __restrict__ W,
    const float* __restrict__ bias, float* __restrict__ p, float* __restrict__ v) {
  __shared__ float xl[32][64];
  int bid = blockIdx.x;           // B * (N/32) = 512
  int b = bid >> 6;
  int n0 = (bid & 63) << 5;
  int tid = threadIdx.x;
  for (int i = tid; i < 32 * 64; i += 256) {
    xl[i >> 6][i & 63] = ft[((size_t)(b * NPT + n0 + (i >> 6))) * CIN + (i & 63)];
  }
  __syncthreads();
  int o = tid & 127, hh = tid >> 7;
  const float4* W1 = (const float4*)&W[o * 2 * CIN];
  const float4* W2 = (const float4*)&W[o * 2 * CIN + CIN];
  float bo = bias[o];
#pragma unroll 1
  for (int t = 0; t < 16; ++t) {
    int node = t * 2 + hh;
    float a1 = 0.f, a2 = 0.f;
#pragma unroll
    for (int c4 = 0; c4 < 16; ++c4) {
      float4 xv = *(const float4*)&xl[node][c4 * 4];
      float4 w1 = W1[c4];
      float4 w2 = W2[c4];
      a1 += xv.x * w1.x + xv.y * w1.y + xv.z * w1.z + xv.w * w1.w;
      a2 += xv.x * w2.x + xv.y * w2.y + xv.z * w2.z + xv.w * w2.w;
    }
    size_t gn = ((size_t)(b * NPT + n0 + node)) * CO + o;
    p[gn] = a1 - a2 + bo;
    v[gn] = a2;
  }
}

// ---------------------------------------------------------------------------
// Kernel B: 16 rows x 2048 cols per block.
// Phase 1: gram via f16 split-2 MFMA into swizzled LDS (conflict-free).
// Phase 2 (tournament pool): per-lane top-3 register scan -> ONE bitonic sort
//   of the 64 lane-bests (descending u64 keys) -> 16 pop/insert rounds, each
//   only ~3 cross-lane ops. LDS rescan only when a lane is popped a 4th time
//   (expected ~0.2x per row); -inf marks in LDS keep rescans exact.
// ---------------------------------------------------------------------------
__global__ __launch_bounds__(1024) void k_dist_topk(
    const _Float16* __restrict__ xh, const _Float16* __restrict__ xl,
    const float* __restrict__ sq, int* __restrict__ idxout) {
  __shared__ float dist[16][NPT];   // 128 KiB
  // XCD-bijective remap: nwg=1024, 1024%8==0 -> each XCD works one batch.
  int bid = (blockIdx.x & 7) * 128 + (blockIdx.x >> 3);
  int b = bid >> 7;
  int rt = (bid & 127) << 4;        // row-tile base
  int tid = threadIdx.x;
  int w = tid >> 6, lane = tid & 63;
  int lr = lane & 15, lg = lane >> 4;   // fragment row index, k-group
  const _Float16* xhb = xh + (size_t)b * NPT * CIN;
  const _Float16* xlb = xl + (size_t)b * NPT * CIN;
  const float* sqb = sq + (size_t)b * NPT;

  // A fragments: rows rt..rt+15, k-chunks 0..31 / 32..63
  const size_t arow = (size_t)(rt + lr) * CIN + lg * 8;
  f16x8 ah0 = *(const f16x8*)(xhb + arow);
  f16x8 ah1 = *(const f16x8*)(xhb + arow + 32);
  f16x8 al0 = *(const f16x8*)(xlb + arow);
  f16x8 al1 = *(const f16x8*)(xlb + arow + 32);
  float4 sqr = *(const float4*)(sqb + rt + lg * 4);
  float sqrv[4] = {sqr.x, sqr.y, sqr.z, sqr.w};

#pragma unroll 1
  for (int t = 0; t < 8; ++t) {
    int c = (w * 8 + t) * 16;
    const size_t brow = (size_t)(c + lr) * CIN + lg * 8;
    f16x8 bh0 = *(const f16x8*)(xhb + brow);
    f16x8 bh1 = *(const f16x8*)(xhb + brow + 32);
    f16x8 bl0 = *(const f16x8*)(xlb + brow);
    f16x8 bl1 = *(const f16x8*)(xlb + brow + 32);
    float sqc = sqb[c + lr];
    f32x4 acc0 = {0.f, 0.f, 0.f, 0.f};   // hi*hi
    f32x4 acc1 = {0.f, 0.f, 0.f, 0.f};   // (hi*lo + lo*hi) * LOSCALE
    acc1 = __builtin_amdgcn_mfma_f32_16x16x32_f16(ah0, bl0, acc1, 0, 0, 0);
    acc1 = __builtin_amdgcn_mfma_f32_16x16x32_f16(al0, bh0, acc1, 0, 0, 0);
    acc1 = __builtin_amdgcn_mfma_f32_16x16x32_f16(ah1, bl1, acc1, 0, 0, 0);
    acc1 = __builtin_amdgcn_mfma_f32_16x16x32_f16(al1, bh1, acc1, 0, 0, 0);
    acc0 = __builtin_amdgcn_mfma_f32_16x16x32_f16(ah0, bh0, acc0, 0, 0, 0);
    acc0 = __builtin_amdgcn_mfma_f32_16x16x32_f16(ah1, bh1, acc0, 0, 0, 0);
    // D mapping (m89-verified): col = lane&15, row = lg*4 + reg
    const float k2 = 2.0f / LOSCALE;
    int colm = c + lr;
    int msw = colm ^ ((colm >> 6) & 31);
#pragma unroll
    for (int q = 0; q < 4; ++q) {
      int r = lg * 4 + q;
      int sw = msw ^ (((r >> 2) & 1) << 4);
      dist[r][sw] = fmaf(acc1[q], k2, 2.f * acc0[q]) - (sqrv[q] + sqc);
    }
  }
  __syncthreads();

  // ---- Phase 2: wave w owns row w; lane owns m = i*64 + lane (i=0..31). ----
  const int rxor = ((w >> 2) & 1) << 4;

  // per-lane top-3 (branch-free; strict > keeps lowest index on ties)
  float b0 = -__builtin_inff(), b1 = -__builtin_inff(), b2 = -__builtin_inff();
  int i0 = 0, i1 = 0, i2 = 0;
#pragma unroll
  for (int i = 0; i < 32; ++i) {
    int m = i * 64 + lane;
    float f = dist[w][m ^ i ^ rxor];
    bool c2 = f > b2, c1 = f > b1, c0 = f > b0;
    b2 = c1 ? b1 : (c2 ? f : b2);  i2 = c1 ? i1 : (c2 ? m : i2);
    b1 = c0 ? b0 : (c1 ? f : b1);  i1 = c0 ? i0 : (c1 ? m : i1);
    b0 = c0 ? f : b0;              i0 = c0 ? m : i0;
  }
  u64 list = packdm(b0, i0);     // pool entry (one per source lane)
  u64 q1 = packdm(b1, i1);       // lane-local queue
  u64 q2 = packdm(b2, i2);

  // bitonic sort of the 64 lane-bests, descending (keys unique)
#pragma unroll
  for (int k = 2; k <= 64; k <<= 1) {
#pragma unroll
    for (int j = k >> 1; j > 0; j >>= 1) {
      u64 pv = shfl_xor_u64(list, j);
      bool up = (lane & k) != 0;
      bool lower = (lane & j) == 0;
      bool gt = list > pv;
      bool keepMine = (lower ^ up) ? gt : !gt;
      list = keepMine ? list : pv;
    }
  }

  int* myidx = idxout + ((size_t)(b * NPT + rt + w)) * KK;
#pragma unroll 1
  for (int it = 0; it < KK; ++it) {
    // pop head (lane 0 holds current max)
    u64 pk = shfl_u64(list, 0);
    int mwin = (int)(0xFFFFFFFFu - (u32)pk);
    int S = mwin & 63;                       // source lane of the winner
    if (lane == 0) {
      dist[w][mwin ^ ((mwin >> 6) & 31) ^ rxor] = -__builtin_inff();
      myidx[it] = mwin;
    }
    // fetch S's next queued value; shift S's queue
    u64 kins = shfl_u64(q1, S);
    if (lane == S) { q1 = q2; q2 = 0; }
    if (kins == 0ULL) {                      // queue empty (wave-uniform): rescan
      asm volatile("s_waitcnt lgkmcnt(0)" ::: "memory");
      int j2 = lane & 31;
      int m2 = j2 * 64 + S;
      float f2 = dist[w][m2 ^ j2 ^ rxor];
      u64 nb = packdm(f2, m2);
#pragma unroll
      for (int s = 1; s < 32; s <<= 1) nb = umax64(nb, shfl_xor_u64(nb, s));
      kins = nb;
    }
    // sorted insert: remaining list (shifted) + kins
    u64 sh = shfl_down_u64(list, 1);
    if (lane == 63) sh = 0;
    u64 bgt = __ballot(sh > kins);
    int cnt = __popcll(bgt);
    list = (lane < cnt) ? sh : ((lane == cnt) ? kins : list);
  }
}

// ---------------------------------------------------------------------------
// Kernel C: per-block partial sums of h, h^2 per channel + per-(node,ch)
// max/min of h.  mn overwrites p in place; mx goes to the dead ft/xh/xl region.
// ---------------------------------------------------------------------------
__global__ __launch_bounds__(256) void k_stats(
    float* p_mn, const float* __restrict__ v, const int* __restrict__ idx,
    float* __restrict__ psums, float* __restrict__ psqs, float* __restrict__ mxb) {
  __shared__ float rs[8][CO];
  __shared__ float rq[8][CO];
  // XCD-bijective remap: nwg=512 -> each XCD's L2 holds exactly one batch's v.
  int bid = (blockIdx.x & 7) * 64 + (blockIdx.x >> 3);
  int b = bid >> 6;
  int n0 = (bid & 63) << 5;
  int tid = threadIdx.x;
  int o4 = tid & 31, ns = tid >> 5;
  const float* vb = v + (size_t)b * NPT * CO;
  float4 s = {0.f, 0.f, 0.f, 0.f};
  float4 qq = {0.f, 0.f, 0.f, 0.f};
#pragma unroll 1
  for (int g = 0; g < 4; ++g) {
    int gn = b * NPT + n0 + g * 8 + ns;
    size_t po = (size_t)gn * CO + o4 * 4;
    float4 p4 = *(const float4*)(p_mn + po);
    const int* id = idx + (size_t)gn * KK;
    float4 mx4 = {-1e30f, -1e30f, -1e30f, -1e30f};
    float4 mn4 = {1e30f, 1e30f, 1e30f, 1e30f};
#pragma unroll 1
    for (int k = 0; k < KK; ++k) {
      int j = id[k];
      float4 v4 = *(const float4*)(vb + (size_t)j * CO + o4 * 4);
      float h0 = fmaxf(p4.x + v4.x, 0.f);
      float h1 = fmaxf(p4.y + v4.y, 0.f);
      float h2 = fmaxf(p4.z + v4.z, 0.f);
      float h3 = fmaxf(p4.w + v4.w, 0.f);
      s.x += h0; s.y += h1; s.z += h2; s.w += h3;
      qq.x += h0 * h0; qq.y += h1 * h1; qq.z += h2 * h2; qq.w += h3 * h3;
      mx4.x = fmaxf(mx4.x, h0); mx4.y = fmaxf(mx4.y, h1);
      mx4.z = fmaxf(mx4.z, h2); mx4.w = fmaxf(mx4.w, h3);
      mn4.x = fminf(mn4.x, h0); mn4.y = fminf(mn4.y, h1);
      mn4.z = fminf(mn4.z, h2); mn4.w = fminf(mn4.w, h3);
    }
    *(float4*)(mxb + po) = mx4;
    *(float4*)(p_mn + po) = mn4;
  }
  rs[ns][o4 * 4 + 0] = s.x;  rs[ns][o4 * 4 + 1] = s.y;
  rs[ns][o4 * 4 + 2] = s.z;  rs[ns][o4 * 4 + 3] = s.w;
  rq[ns][o4 * 4 + 0] = qq.x; rq[ns][o4 * 4 + 1] = qq.y;
  rq[ns][o4 * 4 + 2] = qq.z; rq[ns][o4 * 4 + 3] = qq.w;
  __syncthreads();
  if (tid < CO) {
    float ts = 0.f, tq = 0.f;
#pragma unroll
    for (int i = 0; i < 8; ++i) { ts += rs[i][tid]; tq += rq[i][tid]; }
    psums[(size_t)bid * CO + tid] = ts;
    psqs[(size_t)bid * CO + tid] = tq;
  }
}

// ---------------------------------------------------------------------------
// Kernel E: finalize BN stats -> scale/shift. One block per channel.
// ---------------------------------------------------------------------------
__global__ __launch_bounds__(64) void k_final(
    const float* __restrict__ psums, const float* __restrict__ psqs,
    const float* __restrict__ gamma, const float* __restrict__ beta,
    float* __restrict__ scale, float* __restrict__ shift) {
  int o = blockIdx.x;   // 0..127
  int t = threadIdx.x;  // 0..63
  float s = 0.f, q = 0.f;
  for (int i = t; i < BB * (NPT / 32); i += 64) {
    s += psums[(size_t)i * CO + o];
    q += psqs[(size_t)i * CO + o];
  }
#pragma unroll
  for (int d = 32; d >= 1; d >>= 1) {
    s += __shfl_down(s, d, 64);
    q += __shfl_down(q, d, 64);
  }
  if (t == 0) {
    const float M = (float)(BB * NPT * KK);
    float mean = s / M;
    float var = q / M - mean * mean;
    float sc = gamma[o] * rsqrtf(var + EPSV);
    scale[o] = sc;
    shift[o] = beta[o] - mean * sc;
  }
}

// ---------------------------------------------------------------------------
// Kernel D: out = (sc>=0 ? mx : mn)*sc + sh, transpose-write (B, CO, N).
// ---------------------------------------------------------------------------
__global__ __launch_bounds__(256) void k_out_fast(
    const float* __restrict__ mxb, const float* __restrict__ mnb,
    const float* __restrict__ scale, const float* __restrict__ shift,
    float* __restrict__ out) {
  __shared__ float ob[32][132];
  int bid = blockIdx.x;            // B * (N/32) = 512
  int b = bid >> 6;
  int n0 = (bid & 63) << 5;
  int tid = threadIdx.x;
  int o4 = tid & 31, ns = tid >> 5;
  float4 sc = *(const float4*)(scale + o4 * 4);
  float4 sh = *(const float4*)(shift + o4 * 4);
#pragma unroll
  for (int g = 0; g < 4; ++g) {
    int node = g * 8 + ns;
    size_t po = (size_t)(b * NPT + n0 + node) * CO + o4 * 4;
    float4 mx = *(const float4*)(mxb + po);
    float4 mn = *(const float4*)(mnb + po);
    float4 r;
    r.x = (sc.x >= 0.f ? mx.x : mn.x) * sc.x + sh.x;
    r.y = (sc.y >= 0.f ? mx.y : mn.y) * sc.y + sh.y;
    r.z = (sc.z >= 0.f ? mx.z : mn.z) * sc.z + sh.z;
    r.w = (sc.w >= 0.f ? mx.w : mn.w) * sc.w + sh.w;
    *(float4*)&ob[node][o4 * 4] = r;
  }
  __syncthreads();
  int ni = tid & 31, oh = tid >> 5;
#pragma unroll
  for (int pass = 0; pass < 16; ++pass) {
    int o = pass * 8 + oh;
    out[((size_t)(b * CO + o)) * NPT + n0 + ni] = ob[ni][o];
  }
}

// ---------------------------------------------------------------------------
extern "C" void kernel_launch(void* const* d_in, const int* in_sizes, int n_in,
                              void* d_out, int out_size, void* d_ws, size_t ws_size,
                              hipStream_t stream) {
  const float* x = (const float*)d_in[0];
  const float* W = (const float*)d_in[1];
  const float* bias = (const float*)d_in[2];
  const float* gamma = (const float*)d_in[3];
  const float* beta = (const float*)d_in[4];
  float* out = (float*)d_out;

  char* ws = (char*)d_ws;
  size_t off = 0;
  auto alloc = [&](size_t bytes) {
    void* ptr = ws + off;
    off += (bytes + 255) & ~(size_t)255;
    return ptr;
  };
  float* ft = (float*)alloc(sizeof(float) * BB * NPT * CIN);            // 4 MB
  _Float16* xh = (_Float16*)alloc(sizeof(_Float16) * BB * NPT * CIN);   // 2 MB
  _Float16* xl = (_Float16*)alloc(sizeof(_Float16) * BB * NPT * CIN);   // 2 MB
  float* mx = ft;                                                        // alias (dead after k_dist_topk)
  float* sq = (float*)alloc(sizeof(float) * BB * NPT);                  // 64 KB
  float* p = (float*)alloc(sizeof(float) * BB * NPT * CO);              // 8 MB (becomes mn)
  float* v = (float*)alloc(sizeof(float) * BB * NPT * CO);              // 8 MB
  int* idx = (int*)alloc(sizeof(int) * BB * NPT * KK);                  // 1 MB
  float* psums = (float*)alloc(sizeof(float) * BB * (NPT / 32) * CO);   // 256 KB
  float* psqs = (float*)alloc(sizeof(float) * BB * (NPT / 32) * CO);    // 256 KB
  float* scale = (float*)alloc(sizeof(float) * CO);
  float* shift = (float*)alloc(sizeof(float) * CO);
  (void)ws_size; (void)in_sizes; (void)n_in; (void)out_size;

  hipLaunchKernelGGL(k_prep, dim3(BB * (NPT / 64)), dim3(256), 0, stream, x, ft, sq, xh, xl);
  hipLaunchKernelGGL(k_pv, dim3(BB * (NPT / 32)), dim3(256), 0, stream, ft, W, bias, p, v);
  hipLaunchKernelGGL(k_dist_topk, dim3(BB * (NPT / 16)), dim3(1024), 0, stream, xh, xl, sq, idx);
  hipLaunchKernelGGL(k_stats, dim3(BB * (NPT / 32)), dim3(256), 0, stream, p, v, idx, psums, psqs, mx);
  hipLaunchKernelGGL(k_final, dim3(CO), dim3(64), 0, stream, psums, psqs, gamma, beta, scale, shift);
  hipLaunchKernelGGL(k_out_fast, dim3(BB * (NPT / 32)), dim3(256), 0, stream, mx, p, scale, shift, out);
}

// Round 5
// 161.619 us; speedup vs baseline: 2.6890x; 1.1384x over previous
//
#include <hip/hip_runtime.h>
#include <math.h>

#define BB 8
#define CIN 64
#define CO 128
#define NPT 2048
#define KK 16
#define EPSV 1e-5f
#define LOSCALE 2048.0f   // lo-plane pre-scale: keeps f16 lo out of denormal range

typedef unsigned int u32;
typedef _Float16 f16x8 __attribute__((ext_vector_type(8)));
typedef float f32x4 __attribute__((ext_vector_type(4)));

// ---------------------------------------------------------------------------
// Kernel A+P fused: transpose x (B,C,N), sq[b][n], f16 split planes xh/xl,
// and node-level matmuls p = (W1-W2)x + b, v = W2x  (h_edge = relu(p_i+v_j)).
// ---------------------------------------------------------------------------
__global__ __launch_bounds__(256) void k_prep_pv(
    const float* __restrict__ x, const float* __restrict__ W,
    const float* __restrict__ bias, float* __restrict__ sq,
    _Float16* __restrict__ xh, _Float16* __restrict__ xl,
    float* __restrict__ p, float* __restrict__ v) {
  __shared__ float tile[64][65];    // [ch][node]
  __shared__ float tileT[64][68];   // [node][ch]
  __shared__ float psum[4][64];
  int bid = blockIdx.x;             // B * (N/64) = 256
  int b = bid >> 5;
  int n0 = (bid & 31) << 6;
  int tid = threadIdx.x;
  int q = tid >> 6, lo = tid & 63;
#pragma unroll
  for (int i = 0; i < 16; ++i) {
    int c = i * 4 + q;
    tile[c][lo] = x[((size_t)(b * CIN + c)) * NPT + n0 + lo];
  }
  __syncthreads();
  float ps = 0.f;
#pragma unroll
  for (int i = 0; i < 16; ++i) {
    float t = tile[q * 16 + i][lo];
    ps += t * t;
  }
  psum[q][lo] = ps;
#pragma unroll
  for (int i = 0; i < 16; ++i) {
    int ni = i * 4 + q;
    float val = tile[lo][ni];
    tileT[ni][lo] = val;
    size_t o = ((size_t)(b * NPT + n0 + ni)) * CIN + lo;
    _Float16 h = (_Float16)val;
    xh[o] = h;
    xl[o] = (_Float16)((val - (float)h) * LOSCALE);
  }
  __syncthreads();
  if (q == 0) {
    sq[(size_t)b * NPT + n0 + lo] = psum[0][lo] + psum[1][lo] + psum[2][lo] + psum[3][lo];
  }
  // p/v: each thread owns channel o for 32 of the 64 nodes
  int o = tid & 127, hh = tid >> 7;
  const float4* W1 = (const float4*)&W[o * 2 * CIN];
  const float4* W2 = (const float4*)&W[o * 2 * CIN + CIN];
  float bo = bias[o];
#pragma unroll 1
  for (int t = 0; t < 32; ++t) {
    int node = t * 2 + hh;
    float a1 = 0.f, a2 = 0.f;
#pragma unroll
    for (int c4 = 0; c4 < 16; ++c4) {
      float4 xv = *(const float4*)&tileT[node][c4 * 4];
      float4 w1 = W1[c4];
      float4 w2 = W2[c4];
      a1 += xv.x * w1.x + xv.y * w1.y + xv.z * w1.z + xv.w * w1.w;
      a2 += xv.x * w2.x + xv.y * w2.y + xv.z * w2.z + xv.w * w2.w;
    }
    size_t gn = ((size_t)(b * NPT + n0 + node)) * CO + o;
    p[gn] = a1 - a2 + bo;
    v[gn] = a2;
  }
}

// ---------------------------------------------------------------------------
// Kernel B: 16 rows x 2048 cols per block.
// Phase 1: gram via f16 split-2 MFMA into swizzled LDS.
//   swz(col, r) = col ^ (((col>>5)&7)<<2) ^ (((r>>2)&3)<<2) ^ (((r>>2)&1)<<4)
//   -> stores 2-way (free), phase-2 b128 reads conflict-free.
// Phase 2 (one-shot threshold-compact-sort, no iterative pops):
//   lane owns 32 consecutive cols in regs (8 x ds_read_b128);
//   tau = 16th largest of the 64 lane-maxima (value-only bitonic sort-64);
//   tau <= true 16th value, so C = {v >= tau} contains the exact top-16;
//   count+prefix-scan, compact (val,idx) into dead row LDS, final (val,idx)
//   bitonic sort-64 with lowest-index tie-break (= lax.top_k), store 16 idx.
// ---------------------------------------------------------------------------
__global__ __launch_bounds__(1024) void k_dist_topk(
    const _Float16* __restrict__ xh, const _Float16* __restrict__ xl,
    const float* __restrict__ sq, int* __restrict__ idxout) {
  __shared__ float dist[16][NPT];   // 128 KiB
  // XCD-bijective remap: nwg=1024 -> each XCD works exactly one batch.
  int bid = (blockIdx.x & 7) * 128 + (blockIdx.x >> 3);
  int b = bid >> 7;
  int rt = (bid & 127) << 4;        // row-tile base
  int tid = threadIdx.x;
  int w = tid >> 6, lane = tid & 63;
  int lr = lane & 15, lg = lane >> 4;   // fragment row index, k-group
  const _Float16* xhb = xh + (size_t)b * NPT * CIN;
  const _Float16* xlb = xl + (size_t)b * NPT * CIN;
  const float* sqb = sq + (size_t)b * NPT;

  // A fragments: rows rt..rt+15, k-chunks 0..31 / 32..63
  const size_t arow = (size_t)(rt + lr) * CIN + lg * 8;
  f16x8 ah0 = *(const f16x8*)(xhb + arow);
  f16x8 ah1 = *(const f16x8*)(xhb + arow + 32);
  f16x8 al0 = *(const f16x8*)(xlb + arow);
  f16x8 al1 = *(const f16x8*)(xlb + arow + 32);
  float4 sqr = *(const float4*)(sqb + rt + lg * 4);
  float sqrv[4] = {sqr.x, sqr.y, sqr.z, sqr.w};

#pragma unroll 1
  for (int t = 0; t < 8; ++t) {
    int c = (w * 8 + t) * 16;
    const size_t brow = (size_t)(c + lr) * CIN + lg * 8;
    f16x8 bh0 = *(const f16x8*)(xhb + brow);
    f16x8 bh1 = *(const f16x8*)(xhb + brow + 32);
    f16x8 bl0 = *(const f16x8*)(xlb + brow);
    f16x8 bl1 = *(const f16x8*)(xlb + brow + 32);
    float sqc = sqb[c + lr];
    f32x4 acc0 = {0.f, 0.f, 0.f, 0.f};   // hi*hi
    f32x4 acc1 = {0.f, 0.f, 0.f, 0.f};   // (hi*lo + lo*hi) * LOSCALE
    acc1 = __builtin_amdgcn_mfma_f32_16x16x32_f16(ah0, bl0, acc1, 0, 0, 0);
    acc1 = __builtin_amdgcn_mfma_f32_16x16x32_f16(al0, bh0, acc1, 0, 0, 0);
    acc1 = __builtin_amdgcn_mfma_f32_16x16x32_f16(ah1, bl1, acc1, 0, 0, 0);
    acc1 = __builtin_amdgcn_mfma_f32_16x16x32_f16(al1, bh1, acc1, 0, 0, 0);
    acc0 = __builtin_amdgcn_mfma_f32_16x16x32_f16(ah0, bh0, acc0, 0, 0, 0);
    acc0 = __builtin_amdgcn_mfma_f32_16x16x32_f16(ah1, bh1, acc0, 0, 0, 0);
    // D mapping (m89-verified): col = lane&15, row = lg*4 + reg
    const float k2 = 2.0f / LOSCALE;
    int colm = c + lr;
    int sw = (colm ^ (((colm >> 5) & 7) << 2)) ^ (lg << 2) ^ ((lg & 1) << 4);
#pragma unroll
    for (int q = 0; q < 4; ++q) {
      dist[lg * 4 + q][sw] = fmaf(acc1[q], k2, 2.f * acc0[q]) - (sqrv[q] + sqc);
    }
  }
  __syncthreads();

  // ---- Phase 2: wave w owns row w; lane owns cols [lane*32, lane*32+32). ----
  const int wconst = (((w >> 2) & 3) << 2) ^ (((w >> 2) & 1) << 4);
  float* rowp = &dist[w][0];
  float vals[32];
#pragma unroll
  for (int j = 0; j < 8; ++j) {
    int sw = ((lane * 32 + j * 4) ^ ((lane & 7) << 2)) ^ wconst;
    float4 t4 = *(const float4*)(rowp + sw);
    vals[j * 4 + 0] = t4.x; vals[j * 4 + 1] = t4.y;
    vals[j * 4 + 2] = t4.z; vals[j * 4 + 3] = t4.w;
  }
  float mymax = vals[0];
#pragma unroll
  for (int i = 1; i < 32; ++i) mymax = fmaxf(mymax, vals[i]);

  // value-only bitonic sort-64 of lane maxima, descending
  float s = mymax;
#pragma unroll
  for (int k = 2; k <= 64; k <<= 1) {
#pragma unroll
    for (int j = k >> 1; j > 0; j >>= 1) {
      float pv = __shfl_xor(s, j, 64);
      bool up = (lane & k) != 0;
      bool low = (lane & j) == 0;
      bool gt = s > pv;
      s = ((low != up) ? gt : !gt) ? s : pv;
    }
  }
  float tau = __shfl(s, 15, 64);    // 16th largest lane-max <= true 16th value

  // count + exclusive prefix-scan of per-lane candidate counts
  int cnt = 0;
#pragma unroll
  for (int i = 0; i < 32; ++i) cnt += (vals[i] >= tau) ? 1 : 0;
  int inc = cnt;
#pragma unroll
  for (int d = 1; d < 64; d <<= 1) {
    int t = __shfl_up(inc, d, 64);
    if (lane >= d) inc += t;
  }
  int total = __shfl(inc, 63, 64);
  int off = inc - cnt;

  // compact (val,idx) pairs into the (now dead) row-w LDS region
  float2* buf = (float2*)rowp;
#pragma unroll
  for (int i = 0; i < 32; ++i) {
    if (vals[i] >= tau && off < 112) {
      buf[off] = make_float2(vals[i], __int_as_float(lane * 32 + i));
      ++off;
    }
  }
  asm volatile("s_waitcnt lgkmcnt(0)" ::: "memory");

  const float NINF = -__builtin_inff();
  float cv = NINF;
  int ci = 0x7FFFFFFF;
  int n1 = total < 64 ? total : 64;
  if (lane < n1) {
    float2 pr = buf[lane];
    cv = pr.x; ci = __float_as_int(pr.y);
  }
  // (val,idx) bitonic sort-64, descending by val, ties -> lowest idx
#pragma unroll
  for (int k = 2; k <= 64; k <<= 1) {
#pragma unroll
    for (int j = k >> 1; j > 0; j >>= 1) {
      float pv = __shfl_xor(cv, j, 64);
      int pi = __shfl_xor(ci, j, 64);
      bool up = (lane & k) != 0;
      bool low = (lane & j) == 0;
      bool gt = (cv > pv) || (cv == pv && ci < pi);
      bool keep = (low != up) ? gt : !gt;
      cv = keep ? cv : pv;
      ci = keep ? ci : pi;
    }
  }
  if (total > 64) {   // wave-uniform, astronomically rare: two-batch resort
    int tot2 = total < 112 ? total : 112;
    if (lane >= 16) {
      int src2 = 48 + lane;          // 64 + (lane-16)
      if (src2 < tot2) {
        float2 pr = buf[src2];
        cv = pr.x; ci = __float_as_int(pr.y);
      } else { cv = NINF; ci = 0x7FFFFFFF; }
    }
#pragma unroll
    for (int k = 2; k <= 64; k <<= 1) {
#pragma unroll
      for (int j = k >> 1; j > 0; j >>= 1) {
        float pv = __shfl_xor(cv, j, 64);
        int pi = __shfl_xor(ci, j, 64);
        bool up = (lane & k) != 0;
        bool low = (lane & j) == 0;
        bool gt = (cv > pv) || (cv == pv && ci < pi);
        bool keep = (low != up) ? gt : !gt;
        cv = keep ? cv : pv;
        ci = keep ? ci : pi;
      }
    }
  }
  if (lane < KK) idxout[((size_t)(b * NPT + rt + w)) * KK + lane] = ci;
}

// ---------------------------------------------------------------------------
// Kernel C: per-block partial sums of h, h^2 per channel + per-(node,ch)
// max/min of h.  mn overwrites p in place; mx goes to the dead ft/xh/xl region.
// ---------------------------------------------------------------------------
__global__ __launch_bounds__(256) void k_stats(
    float* p_mn, const float* __restrict__ v, const int* __restrict__ idx,
    float* __restrict__ psums, float* __restrict__ psqs, float* __restrict__ mxb) {
  __shared__ float rs[8][CO];
  __shared__ float rq[8][CO];
  // XCD-bijective remap: nwg=512 -> each XCD's L2 holds exactly one batch's v.
  int bid = (blockIdx.x & 7) * 64 + (blockIdx.x >> 3);
  int b = bid >> 6;
  int n0 = (bid & 63) << 5;
  int tid = threadIdx.x;
  int o4 = tid & 31, ns = tid >> 5;
  const float* vb = v + (size_t)b * NPT * CO;
  float4 s = {0.f, 0.f, 0.f, 0.f};
  float4 qq = {0.f, 0.f, 0.f, 0.f};
#pragma unroll 1
  for (int g = 0; g < 4; ++g) {
    int gn = b * NPT + n0 + g * 8 + ns;
    size_t po = (size_t)gn * CO + o4 * 4;
    float4 p4 = *(const float4*)(p_mn + po);
    const int* id = idx + (size_t)gn * KK;
    float4 mx4 = {-1e30f, -1e30f, -1e30f, -1e30f};
    float4 mn4 = {1e30f, 1e30f, 1e30f, 1e30f};
#pragma unroll 1
    for (int k = 0; k < KK; ++k) {
      int j = id[k];
      float4 v4 = *(const float4*)(vb + (size_t)j * CO + o4 * 4);
      float h0 = fmaxf(p4.x + v4.x, 0.f);
      float h1 = fmaxf(p4.y + v4.y, 0.f);
      float h2 = fmaxf(p4.z + v4.z, 0.f);
      float h3 = fmaxf(p4.w + v4.w, 0.f);
      s.x += h0; s.y += h1; s.z += h2; s.w += h3;
      qq.x += h0 * h0; qq.y += h1 * h1; qq.z += h2 * h2; qq.w += h3 * h3;
      mx4.x = fmaxf(mx4.x, h0); mx4.y = fmaxf(mx4.y, h1);
      mx4.z = fmaxf(mx4.z, h2); mx4.w = fmaxf(mx4.w, h3);
      mn4.x = fminf(mn4.x, h0); mn4.y = fminf(mn4.y, h1);
      mn4.z = fminf(mn4.z, h2); mn4.w = fminf(mn4.w, h3);
    }
    *(float4*)(mxb + po) = mx4;
    *(float4*)(p_mn + po) = mn4;
  }
  rs[ns][o4 * 4 + 0] = s.x;  rs[ns][o4 * 4 + 1] = s.y;
  rs[ns][o4 * 4 + 2] = s.z;  rs[ns][o4 * 4 + 3] = s.w;
  rq[ns][o4 * 4 + 0] = qq.x; rq[ns][o4 * 4 + 1] = qq.y;
  rq[ns][o4 * 4 + 2] = qq.z; rq[ns][o4 * 4 + 3] = qq.w;
  __syncthreads();
  if (tid < CO) {
    float ts = 0.f, tq = 0.f;
#pragma unroll
    for (int i = 0; i < 8; ++i) { ts += rs[i][tid]; tq += rq[i][tid]; }
    psums[(size_t)bid * CO + tid] = ts;
    psqs[(size_t)bid * CO + tid] = tq;
  }
}

// ---------------------------------------------------------------------------
// Kernel E: finalize BN stats -> scale/shift. One block per channel.
// ---------------------------------------------------------------------------
__global__ __launch_bounds__(64) void k_final(
    const float* __restrict__ psums, const float* __restrict__ psqs,
    const float* __restrict__ gamma, const float* __restrict__ beta,
    float* __restrict__ scale, float* __restrict__ shift) {
  int o = blockIdx.x;   // 0..127
  int t = threadIdx.x;  // 0..63
  float s = 0.f, q = 0.f;
  for (int i = t; i < BB * (NPT / 32); i += 64) {
    s += psums[(size_t)i * CO + o];
    q += psqs[(size_t)i * CO + o];
  }
#pragma unroll
  for (int d = 32; d >= 1; d >>= 1) {
    s += __shfl_down(s, d, 64);
    q += __shfl_down(q, d, 64);
  }
  if (t == 0) {
    const float M = (float)(BB * NPT * KK);
    float mean = s / M;
    float var = q / M - mean * mean;
    float sc = gamma[o] * rsqrtf(var + EPSV);
    scale[o] = sc;
    shift[o] = beta[o] - mean * sc;
  }
}

// ---------------------------------------------------------------------------
// Kernel D: out = (sc>=0 ? mx : mn)*sc + sh, transpose-write (B, CO, N).
// ---------------------------------------------------------------------------
__global__ __launch_bounds__(256) void k_out_fast(
    const float* __restrict__ mxb, const float* __restrict__ mnb,
    const float* __restrict__ scale, const float* __restrict__ shift,
    float* __restrict__ out) {
  __shared__ float ob[32][132];
  int bid = blockIdx.x;            // B * (N/32) = 512
  int b = bid >> 6;
  int n0 = (bid & 63) << 5;
  int tid = threadIdx.x;
  int o4 = tid & 31, ns = tid >> 5;
  float4 sc = *(const float4*)(scale + o4 * 4);
  float4 sh = *(const float4*)(shift + o4 * 4);
#pragma unroll
  for (int g = 0; g < 4; ++g) {
    int node = g * 8 + ns;
    size_t po = (size_t)(b * NPT + n0 + node) * CO + o4 * 4;
    float4 mx = *(const float4*)(mxb + po);
    float4 mn = *(const float4*)(mnb + po);
    float4 r;
    r.x = (sc.x >= 0.f ? mx.x : mn.x) * sc.x + sh.x;
    r.y = (sc.y >= 0.f ? mx.y : mn.y) * sc.y + sh.y;
    r.z = (sc.z >= 0.f ? mx.z : mn.z) * sc.z + sh.z;
    r.w = (sc.w >= 0.f ? mx.w : mn.w) * sc.w + sh.w;
    *(float4*)&ob[node][o4 * 4] = r;
  }
  __syncthreads();
  int ni = tid & 31, oh = tid >> 5;
#pragma unroll
  for (int pass = 0; pass < 16; ++pass) {
    int o = pass * 8 + oh;
    out[((size_t)(b * CO + o)) * NPT + n0 + ni] = ob[ni][o];
  }
}

// ---------------------------------------------------------------------------
extern "C" void kernel_launch(void* const* d_in, const int* in_sizes, int n_in,
                              void* d_out, int out_size, void* d_ws, size_t ws_size,
                              hipStream_t stream) {
  const float* x = (const float*)d_in[0];
  const float* W = (const float*)d_in[1];
  const float* bias = (const float*)d_in[2];
  const float* gamma = (const float*)d_in[3];
  const float* beta = (const float*)d_in[4];
  float* out = (float*)d_out;

  char* ws = (char*)d_ws;
  size_t off = 0;
  auto alloc = [&](size_t bytes) {
    void* ptr = ws + off;
    off += (bytes + 255) & ~(size_t)255;
    return ptr;
  };
  // ft region kept (unused) so ft+xh+xl = 8 MB contiguous backing for mx.
  float* ft = (float*)alloc(sizeof(float) * BB * NPT * CIN);            // 4 MB (dead space)
  _Float16* xh = (_Float16*)alloc(sizeof(_Float16) * BB * NPT * CIN);   // 2 MB
  _Float16* xl = (_Float16*)alloc(sizeof(_Float16) * BB * NPT * CIN);   // 2 MB
  float* mx = ft;                                                        // alias (dead after k_dist_topk)
  float* sq = (float*)alloc(sizeof(float) * BB * NPT);                  // 64 KB
  float* p = (float*)alloc(sizeof(float) * BB * NPT * CO);              // 8 MB (becomes mn)
  float* v = (float*)alloc(sizeof(float) * BB * NPT * CO);              // 8 MB
  int* idx = (int*)alloc(sizeof(int) * BB * NPT * KK);                  // 1 MB
  float* psums = (float*)alloc(sizeof(float) * BB * (NPT / 32) * CO);   // 256 KB
  float* psqs = (float*)alloc(sizeof(float) * BB * (NPT / 32) * CO);    // 256 KB
  float* scale = (float*)alloc(sizeof(float) * CO);
  float* shift = (float*)alloc(sizeof(float) * CO);
  (void)ws_size; (void)in_sizes; (void)n_in; (void)out_size;

  hipLaunchKernelGGL(k_prep_pv, dim3(BB * (NPT / 64)), dim3(256), 0, stream,
                     x, W, bias, sq, xh, xl, p, v);
  hipLaunchKernelGGL(k_dist_topk, dim3(BB * (NPT / 16)), dim3(1024), 0, stream, xh, xl, sq, idx);
  hipLaunchKernelGGL(k_stats, dim3(BB * (NPT / 32)), dim3(256), 0, stream, p, v, idx, psums, psqs, mx);
  hipLaunchKernelGGL(k_final, dim3(CO), dim3(64), 0, stream, psums, psqs, gamma, beta, scale, shift);
  hipLaunchKernelGGL(k_out_fast, dim3(BB * (NPT / 32)), dim3(256), 0, stream, mx, p, scale, shift, out);
}

// Round 6
// 147.804 us; speedup vs baseline: 2.9404x; 1.0935x over previous
//
#include <hip/hip_runtime.h>
#include <math.h>

#define BB 8
#define CIN 64
#define CO 128
#define NPT 2048
#define KK 16
#define EPSV 1e-5f
#define LOSCALE 2048.0f   // lo-plane pre-scale: keeps f16 lo out of denormal range

typedef unsigned int u32;
typedef unsigned long long u64;
typedef _Float16 f16x8 __attribute__((ext_vector_type(8)));
typedef float f32x4 __attribute__((ext_vector_type(4)));

// ---------------------------------------------------------------------------
// Kernel A+P fused: transpose x (B,C,N), sq[b][n], f16 split planes xh/xl,
// and node-level matmuls p = (W1-W2)x + b, v = W2x  (h_edge = relu(p_i+v_j)).
// ---------------------------------------------------------------------------
__global__ __launch_bounds__(256) void k_prep_pv(
    const float* __restrict__ x, const float* __restrict__ W,
    const float* __restrict__ bias, float* __restrict__ sq,
    _Float16* __restrict__ xh, _Float16* __restrict__ xl,
    float* __restrict__ p, float* __restrict__ v) {
  __shared__ float tile[64][65];    // [ch][node]
  __shared__ float tileT[64][68];   // [node][ch]
  __shared__ float psum[4][64];
  int bid = blockIdx.x;             // B * (N/64) = 256
  int b = bid >> 5;
  int n0 = (bid & 31) << 6;
  int tid = threadIdx.x;
  int q = tid >> 6, lo = tid & 63;
#pragma unroll
  for (int i = 0; i < 16; ++i) {
    int c = i * 4 + q;
    tile[c][lo] = x[((size_t)(b * CIN + c)) * NPT + n0 + lo];
  }
  __syncthreads();
  float ps = 0.f;
#pragma unroll
  for (int i = 0; i < 16; ++i) {
    float t = tile[q * 16 + i][lo];
    ps += t * t;
  }
  psum[q][lo] = ps;
#pragma unroll
  for (int i = 0; i < 16; ++i) {
    int ni = i * 4 + q;
    float val = tile[lo][ni];
    tileT[ni][lo] = val;
    size_t o = ((size_t)(b * NPT + n0 + ni)) * CIN + lo;
    _Float16 h = (_Float16)val;
    xh[o] = h;
    xl[o] = (_Float16)((val - (float)h) * LOSCALE);
  }
  __syncthreads();
  if (q == 0) {
    sq[(size_t)b * NPT + n0 + lo] = psum[0][lo] + psum[1][lo] + psum[2][lo] + psum[3][lo];
  }
  // p/v: each thread owns channel o for 32 of the 64 nodes
  int o = tid & 127, hh = tid >> 7;
  const float4* W1 = (const float4*)&W[o * 2 * CIN];
  const float4* W2 = (const float4*)&W[o * 2 * CIN + CIN];
  float bo = bias[o];
#pragma unroll 1
  for (int t = 0; t < 32; ++t) {
    int node = t * 2 + hh;
    float a1 = 0.f, a2 = 0.f;
#pragma unroll
    for (int c4 = 0; c4 < 16; ++c4) {
      float4 xv = *(const float4*)&tileT[node][c4 * 4];
      float4 w1 = W1[c4];
      float4 w2 = W2[c4];
      a1 += xv.x * w1.x + xv.y * w1.y + xv.z * w1.z + xv.w * w1.w;
      a2 += xv.x * w2.x + xv.y * w2.y + xv.z * w2.z + xv.w * w2.w;
    }
    size_t gn = ((size_t)(b * NPT + n0 + node)) * CO + o;
    p[gn] = a1 - a2 + bo;
    v[gn] = a2;
  }
}

// ---------------------------------------------------------------------------
// Kernel B: 16 rows x 2048 cols per block.
// Phase 1: gram via f16 split-2 MFMA into swizzled LDS, software-pipelined
//   (iteration t+1's global loads issued before t's MFMAs).
// Phase 2: lane owns 32 cols in regs; tau via 16-step BALLOT BISECTION on
//   ordered-uint lane-maxima (guarantee: cnt(lane-maxes >= tau) >= 16
//   => tau <= true 16th value => C = {v >= tau} covers exact top-16);
//   ballot-ranked compaction into dead row LDS; final (val,idx) bitonic
//   sort (15 stages if |C|<=32, else 21) with lowest-index tie-break.
// ---------------------------------------------------------------------------
__global__ __launch_bounds__(1024) void k_dist_topk(
    const _Float16* __restrict__ xh, const _Float16* __restrict__ xl,
    const float* __restrict__ sq, int* __restrict__ idxout) {
  __shared__ float dist[16][NPT];   // 128 KiB
  // XCD-bijective remap: nwg=1024 -> each XCD works exactly one batch.
  int bid = (blockIdx.x & 7) * 128 + (blockIdx.x >> 3);
  int b = bid >> 7;
  int rt = (bid & 127) << 4;        // row-tile base
  int tid = threadIdx.x;
  int w = tid >> 6, lane = tid & 63;
  int lr = lane & 15, lg = lane >> 4;   // fragment row index, k-group
  const _Float16* xhb = xh + (size_t)b * NPT * CIN;
  const _Float16* xlb = xl + (size_t)b * NPT * CIN;
  const float* sqb = sq + (size_t)b * NPT;

  // A fragments: rows rt..rt+15, k-chunks 0..31 / 32..63
  const size_t arow = (size_t)(rt + lr) * CIN + lg * 8;
  f16x8 ah0 = *(const f16x8*)(xhb + arow);
  f16x8 ah1 = *(const f16x8*)(xhb + arow + 32);
  f16x8 al0 = *(const f16x8*)(xlb + arow);
  f16x8 al1 = *(const f16x8*)(xlb + arow + 32);
  float4 sqr = *(const float4*)(sqb + rt + lg * 4);
  float sqrv[4] = {sqr.x, sqr.y, sqr.z, sqr.w};

  // ---- Phase 1: double-buffered K-loop ----
  f16x8 cb0, cb1, cb2, cb3;
  float csq;
  {
    int c0 = (w * 8) * 16;
    const size_t brow = (size_t)(c0 + lr) * CIN + lg * 8;
    cb0 = *(const f16x8*)(xhb + brow);
    cb1 = *(const f16x8*)(xhb + brow + 32);
    cb2 = *(const f16x8*)(xlb + brow);
    cb3 = *(const f16x8*)(xlb + brow + 32);
    csq = sqb[c0 + lr];
  }
#pragma unroll
  for (int t = 0; t < 8; ++t) {
    f16x8 nb0 = cb0, nb1 = cb1, nb2 = cb2, nb3 = cb3;
    float nsq = csq;
    if (t < 7) {   // prefetch next tile; stays in flight across this tile's MFMAs
      int cn = (w * 8 + t + 1) * 16;
      const size_t brow = (size_t)(cn + lr) * CIN + lg * 8;
      nb0 = *(const f16x8*)(xhb + brow);
      nb1 = *(const f16x8*)(xhb + brow + 32);
      nb2 = *(const f16x8*)(xlb + brow);
      nb3 = *(const f16x8*)(xlb + brow + 32);
      nsq = sqb[cn + lr];
    }
    int c = (w * 8 + t) * 16;
    f32x4 acc0 = {0.f, 0.f, 0.f, 0.f};   // hi*hi
    f32x4 acc1 = {0.f, 0.f, 0.f, 0.f};   // (hi*lo + lo*hi) * LOSCALE
    acc1 = __builtin_amdgcn_mfma_f32_16x16x32_f16(ah0, cb2, acc1, 0, 0, 0);
    acc1 = __builtin_amdgcn_mfma_f32_16x16x32_f16(al0, cb0, acc1, 0, 0, 0);
    acc1 = __builtin_amdgcn_mfma_f32_16x16x32_f16(ah1, cb3, acc1, 0, 0, 0);
    acc1 = __builtin_amdgcn_mfma_f32_16x16x32_f16(al1, cb1, acc1, 0, 0, 0);
    acc0 = __builtin_amdgcn_mfma_f32_16x16x32_f16(ah0, cb0, acc0, 0, 0, 0);
    acc0 = __builtin_amdgcn_mfma_f32_16x16x32_f16(ah1, cb1, acc0, 0, 0, 0);
    // D mapping (m89-verified): col = lane&15, row = lg*4 + q
    const float k2 = 2.0f / LOSCALE;
    int colm = c + lr;
    int sw = (colm ^ (((colm >> 5) & 7) << 2)) ^ (lg << 2) ^ ((lg & 1) << 4);
#pragma unroll
    for (int q = 0; q < 4; ++q) {
      dist[lg * 4 + q][sw] = fmaf(acc1[q], k2, 2.f * acc0[q]) - (sqrv[q] + csq);
    }
    cb0 = nb0; cb1 = nb1; cb2 = nb2; cb3 = nb3; csq = nsq;
  }
  __syncthreads();

  // ---- Phase 2: wave w owns row w; lane owns cols [lane*32, lane*32+32). ----
  const int wconst = (((w >> 2) & 3) << 2) ^ (((w >> 2) & 1) << 4);
  float* rowp = &dist[w][0];
  float vals[32];
#pragma unroll
  for (int j = 0; j < 8; ++j) {
    int sw = ((lane * 32 + j * 4) ^ ((lane & 7) << 2)) ^ wconst;
    float4 t4 = *(const float4*)(rowp + sw);
    vals[j * 4 + 0] = t4.x; vals[j * 4 + 1] = t4.y;
    vals[j * 4 + 2] = t4.z; vals[j * 4 + 3] = t4.w;
  }
  // per-lane max, tree reduction (static indices)
  float mm[16];
#pragma unroll
  for (int i = 0; i < 16; ++i) mm[i] = fmaxf(vals[i], vals[i + 16]);
#pragma unroll
  for (int st = 8; st >= 1; st >>= 1) {
#pragma unroll
    for (int i = 0; i < 8; ++i) {
      if (i < st) mm[i] = fmaxf(mm[i], mm[i + st]);
    }
  }
  u32 ou = __float_as_uint(mm[0]);
  ou = (ou & 0x80000000u) ? ~ou : (ou | 0x80000000u);   // ordered-uint lane max

  // ballot bisection: largest lo (16 high bits) with cnt(lane-maxes >= lo) >= 16
  u32 lo = 0u;
#pragma unroll
  for (int s = 31; s >= 16; --s) {
    u32 cand = lo | (1u << s);
    u64 bal = __ballot(ou >= cand);
    if (__popcll(bal) >= KK) lo = cand;
  }
  u32 tb = (lo & 0x80000000u) ? (lo ^ 0x80000000u) : ~lo;
  float tau = __uint_as_float(tb);   // tau <= true 16th value (exact coverage)

  // ballot-ranked compaction of (val,idx) into dead row-w LDS
  float2* buf = (float2*)rowp;
  const u64 ltmask = (lane == 63) ? ~0ull >> 1 : ((1ull << (lane + (lane == 63 ? 0 : 1))) - 1ull) >> 1;
  // simpler: mask of lanes strictly below me
  const u64 below = (lane == 0) ? 0ull : (~0ull >> (64 - lane));
  (void)ltmask;
  int base = 0;
#pragma unroll
  for (int i = 0; i < 32; ++i) {
    bool pr = vals[i] >= tau;
    u64 mk = __ballot(pr);
    if (pr) {
      int r = base + (int)__popcll(mk & below);
      if (r < 112) buf[r] = make_float2(vals[i], __int_as_float(lane * 32 + i));
    }
    base += (int)__popcll(mk);
  }
  int total = base;
  asm volatile("s_waitcnt lgkmcnt(0)" ::: "memory");

  const float NINF = -__builtin_inff();
  float cv = NINF;
  int ci = 0x7FFFFFFF;
  int n1 = total < 64 ? total : 64;
  if (lane < n1) {
    float2 pr = buf[lane];
    cv = pr.x; ci = __float_as_int(pr.y);
  }

#define PSORT(KMAX)                                                        \
  _Pragma("unroll") for (int k = 2; k <= (KMAX); k <<= 1) {                \
    _Pragma("unroll") for (int j = k >> 1; j > 0; j >>= 1) {               \
      float pv = __shfl_xor(cv, j, 64);                                    \
      int pi = __shfl_xor(ci, j, 64);                                      \
      bool up = (lane & k) != 0;                                           \
      bool lw = (lane & j) == 0;                                           \
      bool gt = (cv > pv) || (cv == pv && ci < pi);                        \
      bool keep = (lw != up) ? gt : !gt;                                   \
      cv = keep ? cv : pv;                                                 \
      ci = keep ? ci : pi;                                                 \
    }                                                                      \
  }

  if (total > 32) {
    PSORT(64)
    if (total > 64) {   // astronomically rare: two-batch resort
      int tot2 = total < 112 ? total : 112;
      if (lane >= 16) {
        int src2 = 48 + lane;
        if (src2 < tot2) {
          float2 pr = buf[src2];
          cv = pr.x; ci = __float_as_int(pr.y);
        } else { cv = NINF; ci = 0x7FFFFFFF; }
      }
      PSORT(64)
    }
  } else {
    PSORT(32)   // lanes 0-31 sort the candidate set; lanes 32-63 sort junk
  }
#undef PSORT

  if (lane < KK) idxout[((size_t)(b * NPT + rt + w)) * KK + lane] = ci;
}

// ---------------------------------------------------------------------------
// Kernel C: per-block partial sums of h, h^2 per channel + per-(node,ch)
// max/min of h.  mn overwrites p in place; mx goes to the dead ft/xh/xl region.
// ---------------------------------------------------------------------------
__global__ __launch_bounds__(256) void k_stats(
    float* p_mn, const float* __restrict__ v, const int* __restrict__ idx,
    float* __restrict__ psums, float* __restrict__ psqs, float* __restrict__ mxb) {
  __shared__ float rs[8][CO];
  __shared__ float rq[8][CO];
  // XCD-bijective remap: nwg=512 -> each XCD's L2 holds exactly one batch's v.
  int bid = (blockIdx.x & 7) * 64 + (blockIdx.x >> 3);
  int b = bid >> 6;
  int n0 = (bid & 63) << 5;
  int tid = threadIdx.x;
  int o4 = tid & 31, ns = tid >> 5;
  const float* vb = v + (size_t)b * NPT * CO;
  float4 s = {0.f, 0.f, 0.f, 0.f};
  float4 qq = {0.f, 0.f, 0.f, 0.f};
#pragma unroll 1
  for (int g = 0; g < 4; ++g) {
    int gn = b * NPT + n0 + g * 8 + ns;
    size_t po = (size_t)gn * CO + o4 * 4;
    float4 p4 = *(const float4*)(p_mn + po);
    const int* id = idx + (size_t)gn * KK;
    int4 j0 = *(const int4*)(id);
    int4 j1 = *(const int4*)(id + 4);
    int4 j2 = *(const int4*)(id + 8);
    int4 j3 = *(const int4*)(id + 12);
    int jj[16] = {j0.x, j0.y, j0.z, j0.w, j1.x, j1.y, j1.z, j1.w,
                  j2.x, j2.y, j2.z, j2.w, j3.x, j3.y, j3.z, j3.w};
    float4 mx4 = {-1e30f, -1e30f, -1e30f, -1e30f};
    float4 mn4 = {1e30f, 1e30f, 1e30f, 1e30f};
#pragma unroll
    for (int k = 0; k < KK; ++k) {   // 16 independent gathers in flight
      float4 v4 = *(const float4*)(vb + (size_t)jj[k] * CO + o4 * 4);
      float h0 = fmaxf(p4.x + v4.x, 0.f);
      float h1 = fmaxf(p4.y + v4.y, 0.f);
      float h2 = fmaxf(p4.z + v4.z, 0.f);
      float h3 = fmaxf(p4.w + v4.w, 0.f);
      s.x += h0; s.y += h1; s.z += h2; s.w += h3;
      qq.x += h0 * h0; qq.y += h1 * h1; qq.z += h2 * h2; qq.w += h3 * h3;
      mx4.x = fmaxf(mx4.x, h0); mx4.y = fmaxf(mx4.y, h1);
      mx4.z = fmaxf(mx4.z, h2); mx4.w = fmaxf(mx4.w, h3);
      mn4.x = fminf(mn4.x, h0); mn4.y = fminf(mn4.y, h1);
      mn4.z = fminf(mn4.z, h2); mn4.w = fminf(mn4.w, h3);
    }
    *(float4*)(mxb + po) = mx4;
    *(float4*)(p_mn + po) = mn4;
  }
  rs[ns][o4 * 4 + 0] = s.x;  rs[ns][o4 * 4 + 1] = s.y;
  rs[ns][o4 * 4 + 2] = s.z;  rs[ns][o4 * 4 + 3] = s.w;
  rq[ns][o4 * 4 + 0] = qq.x; rq[ns][o4 * 4 + 1] = qq.y;
  rq[ns][o4 * 4 + 2] = qq.z; rq[ns][o4 * 4 + 3] = qq.w;
  __syncthreads();
  if (tid < CO) {
    float ts = 0.f, tq = 0.f;
#pragma unroll
    for (int i = 0; i < 8; ++i) { ts += rs[i][tid]; tq += rq[i][tid]; }
    psums[(size_t)bid * CO + tid] = ts;
    psqs[(size_t)bid * CO + tid] = tq;
  }
}

// ---------------------------------------------------------------------------
// Kernel E: finalize BN stats -> scale/shift. One block per channel.
// ---------------------------------------------------------------------------
__global__ __launch_bounds__(64) void k_final(
    const float* __restrict__ psums, const float* __restrict__ psqs,
    const float* __restrict__ gamma, const float* __restrict__ beta,
    float* __restrict__ scale, float* __restrict__ shift) {
  int o = blockIdx.x;   // 0..127
  int t = threadIdx.x;  // 0..63
  float s = 0.f, q = 0.f;
  for (int i = t; i < BB * (NPT / 32); i += 64) {
    s += psums[(size_t)i * CO + o];
    q += psqs[(size_t)i * CO + o];
  }
#pragma unroll
  for (int d = 32; d >= 1; d >>= 1) {
    s += __shfl_down(s, d, 64);
    q += __shfl_down(q, d, 64);
  }
  if (t == 0) {
    const float M = (float)(BB * NPT * KK);
    float mean = s / M;
    float var = q / M - mean * mean;
    float sc = gamma[o] * rsqrtf(var + EPSV);
    scale[o] = sc;
    shift[o] = beta[o] - mean * sc;
  }
}

// ---------------------------------------------------------------------------
// Kernel D: out = (sc>=0 ? mx : mn)*sc + sh, transpose-write (B, CO, N).
// ---------------------------------------------------------------------------
__global__ __launch_bounds__(256) void k_out_fast(
    const float* __restrict__ mxb, const float* __restrict__ mnb,
    const float* __restrict__ scale, const float* __restrict__ shift,
    float* __restrict__ out) {
  __shared__ float ob[32][132];
  int bid = blockIdx.x;            // B * (N/32) = 512
  int b = bid >> 6;
  int n0 = (bid & 63) << 5;
  int tid = threadIdx.x;
  int o4 = tid & 31, ns = tid >> 5;
  float4 sc = *(const float4*)(scale + o4 * 4);
  float4 sh = *(const float4*)(shift + o4 * 4);
#pragma unroll
  for (int g = 0; g < 4; ++g) {
    int node = g * 8 + ns;
    size_t po = (size_t)(b * NPT + n0 + node) * CO + o4 * 4;
    float4 mx = *(const float4*)(mxb + po);
    float4 mn = *(const float4*)(mnb + po);
    float4 r;
    r.x = (sc.x >= 0.f ? mx.x : mn.x) * sc.x + sh.x;
    r.y = (sc.y >= 0.f ? mx.y : mn.y) * sc.y + sh.y;
    r.z = (sc.z >= 0.f ? mx.z : mn.z) * sc.z + sh.z;
    r.w = (sc.w >= 0.f ? mx.w : mn.w) * sc.w + sh.w;
    *(float4*)&ob[node][o4 * 4] = r;
  }
  __syncthreads();
  int ni = tid & 31, oh = tid >> 5;
#pragma unroll
  for (int pass = 0; pass < 16; ++pass) {
    int o = pass * 8 + oh;
    out[((size_t)(b * CO + o)) * NPT + n0 + ni] = ob[ni][o];
  }
}

// ---------------------------------------------------------------------------
extern "C" void kernel_launch(void* const* d_in, const int* in_sizes, int n_in,
                              void* d_out, int out_size, void* d_ws, size_t ws_size,
                              hipStream_t stream) {
  const float* x = (const float*)d_in[0];
  const float* W = (const float*)d_in[1];
  const float* bias = (const float*)d_in[2];
  const float* gamma = (const float*)d_in[3];
  const float* beta = (const float*)d_in[4];
  float* out = (float*)d_out;

  char* ws = (char*)d_ws;
  size_t off = 0;
  auto alloc = [&](size_t bytes) {
    void* ptr = ws + off;
    off += (bytes + 255) & ~(size_t)255;
    return ptr;
  };
  // ft region kept (unused) so ft+xh+xl = 8 MB contiguous backing for mx.
  float* ft = (float*)alloc(sizeof(float) * BB * NPT * CIN);            // 4 MB (dead space)
  _Float16* xh = (_Float16*)alloc(sizeof(_Float16) * BB * NPT * CIN);   // 2 MB
  _Float16* xl = (_Float16*)alloc(sizeof(_Float16) * BB * NPT * CIN);   // 2 MB
  float* mx = ft;                                                        // alias (dead after k_dist_topk)
  float* sq = (float*)alloc(sizeof(float) * BB * NPT);                  // 64 KB
  float* p = (float*)alloc(sizeof(float) * BB * NPT * CO);              // 8 MB (becomes mn)
  float* v = (float*)alloc(sizeof(float) * BB * NPT * CO);              // 8 MB
  int* idx = (int*)alloc(sizeof(int) * BB * NPT * KK);                  // 1 MB
  float* psums = (float*)alloc(sizeof(float) * BB * (NPT / 32) * CO);   // 256 KB
  float* psqs = (float*)alloc(sizeof(float) * BB * (NPT / 32) * CO);    // 256 KB
  float* scale = (float*)alloc(sizeof(float) * CO);
  float* shift = (float*)alloc(sizeof(float) * CO);
  (void)ws_size; (void)in_sizes; (void)n_in; (void)out_size;

  hipLaunchKernelGGL(k_prep_pv, dim3(BB * (NPT / 64)), dim3(256), 0, stream,
                     x, W, bias, sq, xh, xl, p, v);
  hipLaunchKernelGGL(k_dist_topk, dim3(BB * (NPT / 16)), dim3(1024), 0, stream, xh, xl, sq, idx);
  hipLaunchKernelGGL(k_stats, dim3(BB * (NPT / 32)), dim3(256), 0, stream, p, v, idx, psums, psqs, mx);
  hipLaunchKernelGGL(k_final, dim3(CO), dim3(64), 0, stream, psums, psqs, gamma, beta, scale, shift);
  hipLaunchKernelGGL(k_out_fast, dim3(BB * (NPT / 32)), dim3(256), 0, stream, mx, p, scale, shift, out);
}

// Round 7
// 113.488 us; speedup vs baseline: 3.8295x; 1.3024x over previous
//
#include <hip/hip_runtime.h>
#include <math.h>

#define BB 8
#define CIN 64
#define CO 128
#define NPT 2048
#define KK 16
#define EPSV 1e-5f
#define LOSCALE 2048.0f   // lo-plane pre-scale: keeps f16 lo out of denormal range

typedef unsigned int u32;
typedef unsigned long long u64;
typedef _Float16 f16x8 __attribute__((ext_vector_type(8)));
typedef float f32x4 __attribute__((ext_vector_type(4)));

// ---------------------------------------------------------------------------
// Kernel A+P fused: transpose x (B,C,N), sq[b][n], f16 split planes xh/xl,
// and node-level matmuls p = (W1-W2)x + b, v = W2x  (h_edge = relu(p_i+v_j)).
// ---------------------------------------------------------------------------
__global__ __launch_bounds__(256) void k_prep_pv(
    const float* __restrict__ x, const float* __restrict__ W,
    const float* __restrict__ bias, float* __restrict__ sq,
    _Float16* __restrict__ xh, _Float16* __restrict__ xl,
    float* __restrict__ p, float* __restrict__ v) {
  __shared__ float tile[64][65];    // [ch][node]
  __shared__ float tileT[64][68];   // [node][ch]
  __shared__ float psum[4][64];
  int bid = blockIdx.x;             // B * (N/64) = 256
  int b = bid >> 5;
  int n0 = (bid & 31) << 6;
  int tid = threadIdx.x;
  int q = tid >> 6, lo = tid & 63;
#pragma unroll
  for (int i = 0; i < 16; ++i) {
    int c = i * 4 + q;
    tile[c][lo] = x[((size_t)(b * CIN + c)) * NPT + n0 + lo];
  }
  __syncthreads();
  float ps = 0.f;
#pragma unroll
  for (int i = 0; i < 16; ++i) {
    float t = tile[q * 16 + i][lo];
    ps += t * t;
  }
  psum[q][lo] = ps;
#pragma unroll
  for (int i = 0; i < 16; ++i) {
    int ni = i * 4 + q;
    float val = tile[lo][ni];
    tileT[ni][lo] = val;
    size_t o = ((size_t)(b * NPT + n0 + ni)) * CIN + lo;
    _Float16 h = (_Float16)val;
    xh[o] = h;
    xl[o] = (_Float16)((val - (float)h) * LOSCALE);
  }
  __syncthreads();
  if (q == 0) {
    sq[(size_t)b * NPT + n0 + lo] = psum[0][lo] + psum[1][lo] + psum[2][lo] + psum[3][lo];
  }
  int o = tid & 127, hh = tid >> 7;
  const float4* W1 = (const float4*)&W[o * 2 * CIN];
  const float4* W2 = (const float4*)&W[o * 2 * CIN + CIN];
  float bo = bias[o];
#pragma unroll 1
  for (int t = 0; t < 32; ++t) {
    int node = t * 2 + hh;
    float a1 = 0.f, a2 = 0.f;
#pragma unroll
    for (int c4 = 0; c4 < 16; ++c4) {
      float4 xv = *(const float4*)&tileT[node][c4 * 4];
      float4 w1 = W1[c4];
      float4 w2 = W2[c4];
      a1 += xv.x * w1.x + xv.y * w1.y + xv.z * w1.z + xv.w * w1.w;
      a2 += xv.x * w2.x + xv.y * w2.y + xv.z * w2.z + xv.w * w2.w;
    }
    size_t gn = ((size_t)(b * NPT + n0 + node)) * CO + o;
    p[gn] = a1 - a2 + bo;
    v[gn] = a2;
  }
}

// ---------------------------------------------------------------------------
// Kernel B (redesigned): 16 rows x 2048 cols per block, 16 waves, NO dist LDS.
// Phase 1: per-wave private LDS tile double-buffer filled by coalesced
//   global_load_lds (counted vmcnt(4) waits, pre-swizzled source, linear dest;
//   ds_read_b128 frag reads use the same XOR -> ~conflict-free). MFMA output
//   distances stay in registers (vals[32] = 4 rows x 8 cols per lane).
// Phase 2: per-lane row maxes -> shfl_xor cluster reduce -> 64 sub-pool maxes
//   per row (4 KB LDS); tau per row via 16-step ballot bisection (exact
//   coverage: cnt(pool-maxes >= tau) >= 16 => tau <= true 16th value);
//   LDS-atomic compaction of candidates (order-independent after final sort);
//   final (val,idx) bitonic sort, lowest-index tie-break (= lax.top_k).
// ---------------------------------------------------------------------------
__global__ __launch_bounds__(1024) void k_dist_topk(
    const _Float16* __restrict__ xh, const _Float16* __restrict__ xl,
    const float* __restrict__ sq, int* __restrict__ idxout) {
  __shared__ uint4 tiles[16][2][256];   // 128 KiB: per-wave 2 x 4KB tile buffers
  __shared__ float submax[16][64];      // 4 KiB: 64 sub-pool maxes per row
  __shared__ float2 cand[16][96];       // 12 KiB: candidate (val,idx) per row
  __shared__ int cnt[16];
  __shared__ float tauf[16];

  // XCD-bijective remap: nwg=1024 -> each XCD works exactly one batch.
  int bid = (blockIdx.x & 7) * 128 + (blockIdx.x >> 3);
  int b = bid >> 7;
  int rt = (bid & 127) << 4;            // row-tile base
  int tid = threadIdx.x;
  int w = tid >> 6, lane = tid & 63;
  int lr = lane & 15, lg = lane >> 4;
  const _Float16* xhb = xh + (size_t)b * NPT * CIN;
  const _Float16* xlb = xl + (size_t)b * NPT * CIN;
  const float* sqb = sq + (size_t)b * NPT;

  if (tid < 16) cnt[tid] = 0;

  // A fragments: rows rt..rt+15, k-chunks 0..31 / 32..63 (VMEM, once)
  const size_t arow = (size_t)(rt + lr) * CIN + lg * 8;
  f16x8 ah0 = *(const f16x8*)(xhb + arow);
  f16x8 ah1 = *(const f16x8*)(xhb + arow + 32);
  f16x8 al0 = *(const f16x8*)(xlb + arow);
  f16x8 al1 = *(const f16x8*)(xlb + arow + 32);
  float4 sqr = *(const float4*)(sqb + rt + lg * 4);
  float sqrv[4] = {sqr.x, sqr.y, sqr.z, sqr.w};
  float csqs[8];
#pragma unroll
  for (int t = 0; t < 8; ++t) csqs[t] = sqb[(w * 8 + t) * 16 + lr];

  // gll source swizzle (involution at 16B units): lds[u^s(u)] = src[u]
  const char* xhB = (const char*)xhb;
  const char* xlB = (const char*)xlb;
  const int su = (lane ^ ((lane >> 3) & 7)) * 16;

#define ISSUE_TILE(T)                                                          \
  {                                                                            \
    const int tb_ = (w * 8 + (T)) * 2048;                                      \
    uint4* buf_ = &tiles[w][(T) & 1][0];                                       \
    __builtin_amdgcn_global_load_lds((const uint4*)(xhB + tb_ + su),           \
                                     buf_, 16, 0, 0);                          \
    __builtin_amdgcn_global_load_lds((const uint4*)(xhB + tb_ + 1024 + su),    \
                                     buf_ + 64, 16, 0, 0);                     \
    __builtin_amdgcn_global_load_lds((const uint4*)(xlB + tb_ + su),           \
                                     buf_ + 128, 16, 0, 0);                    \
    __builtin_amdgcn_global_load_lds((const uint4*)(xlB + tb_ + 1024 + su),    \
                                     buf_ + 192, 16, 0, 0);                    \
  }

  ISSUE_TILE(0)
  ISSUE_TILE(1)

  const int uh0 = lr * 8 + (lg ^ (lr & 7));
  const int uh1 = lr * 8 + ((lg + 4) ^ (lr & 7));
  float vals[32];

#pragma unroll
  for (int t = 0; t < 8; ++t) {
    if (t < 7) { asm volatile("s_waitcnt vmcnt(4)" ::: "memory"); }
    else       { asm volatile("s_waitcnt vmcnt(0)" ::: "memory"); }
    __builtin_amdgcn_sched_barrier(0);
    const uint4* bufr = &tiles[w][t & 1][0];
    f16x8 bh0 = *(const f16x8*)(bufr + uh0);
    f16x8 bh1 = *(const f16x8*)(bufr + uh1);
    f16x8 bl0 = *(const f16x8*)(bufr + 128 + uh0);
    f16x8 bl1 = *(const f16x8*)(bufr + 128 + uh1);
    f32x4 acc0 = {0.f, 0.f, 0.f, 0.f};   // hi*hi
    f32x4 acc1 = {0.f, 0.f, 0.f, 0.f};   // (hi*lo + lo*hi) * LOSCALE
    acc1 = __builtin_amdgcn_mfma_f32_16x16x32_f16(ah0, bl0, acc1, 0, 0, 0);
    acc1 = __builtin_amdgcn_mfma_f32_16x16x32_f16(al0, bh0, acc1, 0, 0, 0);
    acc1 = __builtin_amdgcn_mfma_f32_16x16x32_f16(ah1, bl1, acc1, 0, 0, 0);
    acc1 = __builtin_amdgcn_mfma_f32_16x16x32_f16(al1, bh1, acc1, 0, 0, 0);
    acc0 = __builtin_amdgcn_mfma_f32_16x16x32_f16(ah0, bh0, acc0, 0, 0, 0);
    acc0 = __builtin_amdgcn_mfma_f32_16x16x32_f16(ah1, bh1, acc0, 0, 0, 0);
    const float k2 = 2.0f / LOSCALE;
#pragma unroll
    for (int q = 0; q < 4; ++q) {
      vals[t * 4 + q] = fmaf(acc1[q], k2, 2.f * acc0[q]) - (sqrv[q] + csqs[t]);
    }
    // ds_reads of this buffer are complete before re-issuing into it
    asm volatile("s_waitcnt lgkmcnt(0)" ::: "memory");
    __builtin_amdgcn_sched_barrier(0);
    if (t == 0) ISSUE_TILE(2)
    if (t == 1) ISSUE_TILE(3)
    if (t == 2) ISSUE_TILE(4)
    if (t == 3) ISSUE_TILE(5)
    if (t == 4) ISSUE_TILE(6)
    if (t == 5) ISSUE_TILE(7)
  }
#undef ISSUE_TILE

  // ---- Phase 2a: sub-pool maxes (pool = 4-lane cluster x 8 tiles = 32 cols)
  float rmax[4];
#pragma unroll
  for (int q = 0; q < 4; ++q) {
    float m = vals[q];
#pragma unroll
    for (int t = 1; t < 8; ++t) m = fmaxf(m, vals[t * 4 + q]);
    m = fmaxf(m, __shfl_xor(m, 1, 64));
    m = fmaxf(m, __shfl_xor(m, 2, 64));
    rmax[q] = m;
  }
  if ((lr & 3) == 0) {
    int pool = w * 4 + (lr >> 2);
#pragma unroll
    for (int q = 0; q < 4; ++q) submax[lg * 4 + q][pool] = rmax[q];
  }
  __syncthreads();

  // ---- Phase 2b: tau per row via ballot bisection (wave w owns row w)
  {
    u32 ou = __float_as_uint(submax[w][lane]);
    ou = (ou & 0x80000000u) ? ~ou : (ou | 0x80000000u);
    u32 lo = 0u;
#pragma unroll
    for (int s2 = 31; s2 >= 16; --s2) {
      u32 cd = lo | (1u << s2);
      u64 bal = __ballot(ou >= cd);
      if (__popcll(bal) >= KK) lo = cd;
    }
    u32 tb = (lo & 0x80000000u) ? (lo ^ 0x80000000u) : ~lo;
    if (lane == 0) tauf[w] = __uint_as_float(tb);
  }
  __syncthreads();

  // ---- Phase 2c: atomic compaction of candidates >= tau (rare, ~25/row)
  {
    float tq[4];
#pragma unroll
    for (int q = 0; q < 4; ++q) tq[q] = tauf[lg * 4 + q];
#pragma unroll
    for (int t = 0; t < 8; ++t) {
#pragma unroll
      for (int q = 0; q < 4; ++q) {
        float vv = vals[t * 4 + q];
        if (vv >= tq[q]) {
          int r = lg * 4 + q;
          int pos = atomicAdd(&cnt[r], 1);
          if (pos < 96) cand[r][pos] = make_float2(vv, __int_as_float((w * 8 + t) * 16 + lr));
        }
      }
    }
  }
  __syncthreads();

  // ---- Phase 2d: final exact (val,idx) sort, wave w sorts row w
  int total = cnt[w];
  if (total > 96) total = 96;
  const float NINF = -__builtin_inff();
  float cv = NINF;
  int ci = 0x7FFFFFFF;
  int n1 = total < 64 ? total : 64;
  if (lane < n1) {
    float2 pr = cand[w][lane];
    cv = pr.x; ci = __float_as_int(pr.y);
  }

#define PSORT(KMAX)                                                        \
  _Pragma("unroll") for (int k = 2; k <= (KMAX); k <<= 1) {                \
    _Pragma("unroll") for (int j = k >> 1; j > 0; j >>= 1) {               \
      float pv = __shfl_xor(cv, j, 64);                                    \
      int pi = __shfl_xor(ci, j, 64);                                      \
      bool up = (lane & k) != 0;                                           \
      bool lw = (lane & j) == 0;                                           \
      bool gt = (cv > pv) || (cv == pv && ci < pi);                        \
      bool keep = (lw != up) ? gt : !gt;                                   \
      cv = keep ? cv : pv;                                                 \
      ci = keep ? ci : pi;                                                 \
    }                                                                      \
  }

  if (total > 32) {
    PSORT(64)
    if (total > 64) {   // astronomically rare: two-batch resort
      if (lane >= 16) {
        int src2 = 48 + lane;
        if (src2 < total) {
          float2 pr = cand[w][src2];
          cv = pr.x; ci = __float_as_int(pr.y);
        } else { cv = NINF; ci = 0x7FFFFFFF; }
      }
      PSORT(64)
    }
  } else {
    PSORT(32)
  }
#undef PSORT

  if (lane < KK) idxout[((size_t)(b * NPT + rt + w)) * KK + lane] = ci;
}

// ---------------------------------------------------------------------------
// Kernel C: per-block partial sums of h, h^2 per channel + per-(node,ch)
// max/min of h.  mn overwrites p in place; mx goes to the dead ft/xh/xl region.
// ---------------------------------------------------------------------------
__global__ __launch_bounds__(256) void k_stats(
    float* p_mn, const float* __restrict__ v, const int* __restrict__ idx,
    float* __restrict__ psums, float* __restrict__ psqs, float* __restrict__ mxb) {
  __shared__ float rs[8][CO];
  __shared__ float rq[8][CO];
  int bid = (blockIdx.x & 7) * 64 + (blockIdx.x >> 3);
  int b = bid >> 6;
  int n0 = (bid & 63) << 5;
  int tid = threadIdx.x;
  int o4 = tid & 31, ns = tid >> 5;
  const float* vb = v + (size_t)b * NPT * CO;
  float4 s = {0.f, 0.f, 0.f, 0.f};
  float4 qq = {0.f, 0.f, 0.f, 0.f};
#pragma unroll 1
  for (int g = 0; g < 4; ++g) {
    int gn = b * NPT + n0 + g * 8 + ns;
    size_t po = (size_t)gn * CO + o4 * 4;
    float4 p4 = *(const float4*)(p_mn + po);
    const int* id = idx + (size_t)gn * KK;
    int4 j0 = *(const int4*)(id);
    int4 j1 = *(const int4*)(id + 4);
    int4 j2 = *(const int4*)(id + 8);
    int4 j3 = *(const int4*)(id + 12);
    int jj[16] = {j0.x, j0.y, j0.z, j0.w, j1.x, j1.y, j1.z, j1.w,
                  j2.x, j2.y, j2.z, j2.w, j3.x, j3.y, j3.z, j3.w};
    float4 mx4 = {-1e30f, -1e30f, -1e30f, -1e30f};
    float4 mn4 = {1e30f, 1e30f, 1e30f, 1e30f};
#pragma unroll
    for (int k = 0; k < KK; ++k) {
      float4 v4 = *(const float4*)(vb + (size_t)jj[k] * CO + o4 * 4);
      float h0 = fmaxf(p4.x + v4.x, 0.f);
      float h1 = fmaxf(p4.y + v4.y, 0.f);
      float h2 = fmaxf(p4.z + v4.z, 0.f);
      float h3 = fmaxf(p4.w + v4.w, 0.f);
      s.x += h0; s.y += h1; s.z += h2; s.w += h3;
      qq.x += h0 * h0; qq.y += h1 * h1; qq.z += h2 * h2; qq.w += h3 * h3;
      mx4.x = fmaxf(mx4.x, h0); mx4.y = fmaxf(mx4.y, h1);
      mx4.z = fmaxf(mx4.z, h2); mx4.w = fmaxf(mx4.w, h3);
      mn4.x = fminf(mn4.x, h0); mn4.y = fminf(mn4.y, h1);
      mn4.z = fminf(mn4.z, h2); mn4.w = fminf(mn4.w, h3);
    }
    *(float4*)(mxb + po) = mx4;
    *(float4*)(p_mn + po) = mn4;
  }
  rs[ns][o4 * 4 + 0] = s.x;  rs[ns][o4 * 4 + 1] = s.y;
  rs[ns][o4 * 4 + 2] = s.z;  rs[ns][o4 * 4 + 3] = s.w;
  rq[ns][o4 * 4 + 0] = qq.x; rq[ns][o4 * 4 + 1] = qq.y;
  rq[ns][o4 * 4 + 2] = qq.z; rq[ns][o4 * 4 + 3] = qq.w;
  __syncthreads();
  if (tid < CO) {
    float ts = 0.f, tq = 0.f;
#pragma unroll
    for (int i = 0; i < 8; ++i) { ts += rs[i][tid]; tq += rq[i][tid]; }
    psums[(size_t)bid * CO + tid] = ts;
    psqs[(size_t)bid * CO + tid] = tq;
  }
}

// ---------------------------------------------------------------------------
// Kernel E: finalize BN stats -> scale/shift. One block per channel.
// ---------------------------------------------------------------------------
__global__ __launch_bounds__(64) void k_final(
    const float* __restrict__ psums, const float* __restrict__ psqs,
    const float* __restrict__ gamma, const float* __restrict__ beta,
    float* __restrict__ scale, float* __restrict__ shift) {
  int o = blockIdx.x;
  int t = threadIdx.x;
  float s = 0.f, q = 0.f;
  for (int i = t; i < BB * (NPT / 32); i += 64) {
    s += psums[(size_t)i * CO + o];
    q += psqs[(size_t)i * CO + o];
  }
#pragma unroll
  for (int d = 32; d >= 1; d >>= 1) {
    s += __shfl_down(s, d, 64);
    q += __shfl_down(q, d, 64);
  }
  if (t == 0) {
    const float M = (float)(BB * NPT * KK);
    float mean = s / M;
    float var = q / M - mean * mean;
    float sc = gamma[o] * rsqrtf(var + EPSV);
    scale[o] = sc;
    shift[o] = beta[o] - mean * sc;
  }
}

// ---------------------------------------------------------------------------
// Kernel D: out = (sc>=0 ? mx : mn)*sc + sh, transpose-write (B, CO, N).
// ---------------------------------------------------------------------------
__global__ __launch_bounds__(256) void k_out_fast(
    const float* __restrict__ mxb, const float* __restrict__ mnb,
    const float* __restrict__ scale, const float* __restrict__ shift,
    float* __restrict__ out) {
  __shared__ float ob[32][132];
  int bid = blockIdx.x;
  int b = bid >> 6;
  int n0 = (bid & 63) << 5;
  int tid = threadIdx.x;
  int o4 = tid & 31, ns = tid >> 5;
  float4 sc = *(const float4*)(scale + o4 * 4);
  float4 sh = *(const float4*)(shift + o4 * 4);
#pragma unroll
  for (int g = 0; g < 4; ++g) {
    int node = g * 8 + ns;
    size_t po = (size_t)(b * NPT + n0 + node) * CO + o4 * 4;
    float4 mx = *(const float4*)(mxb + po);
    float4 mn = *(const float4*)(mnb + po);
    float4 r;
    r.x = (sc.x >= 0.f ? mx.x : mn.x) * sc.x + sh.x;
    r.y = (sc.y >= 0.f ? mx.y : mn.y) * sc.y + sh.y;
    r.z = (sc.z >= 0.f ? mx.z : mn.z) * sc.z + sh.z;
    r.w = (sc.w >= 0.f ? mx.w : mn.w) * sc.w + sh.w;
    *(float4*)&ob[node][o4 * 4] = r;
  }
  __syncthreads();
  int ni = tid & 31, oh = tid >> 5;
#pragma unroll
  for (int pass = 0; pass < 16; ++pass) {
    int o = pass * 8 + oh;
    out[((size_t)(b * CO + o)) * NPT + n0 + ni] = ob[ni][o];
  }
}

// ---------------------------------------------------------------------------
extern "C" void kernel_launch(void* const* d_in, const int* in_sizes, int n_in,
                              void* d_out, int out_size, void* d_ws, size_t ws_size,
                              hipStream_t stream) {
  const float* x = (const float*)d_in[0];
  const float* W = (const float*)d_in[1];
  const float* bias = (const float*)d_in[2];
  const float* gamma = (const float*)d_in[3];
  const float* beta = (const float*)d_in[4];
  float* out = (float*)d_out;

  char* ws = (char*)d_ws;
  size_t off = 0;
  auto alloc = [&](size_t bytes) {
    void* ptr = ws + off;
    off += (bytes + 255) & ~(size_t)255;
    return ptr;
  };
  // ft region kept (unused) so ft+xh+xl = 8 MB contiguous backing for mx.
  float* ft = (float*)alloc(sizeof(float) * BB * NPT * CIN);            // 4 MB (dead space)
  _Float16* xh = (_Float16*)alloc(sizeof(_Float16) * BB * NPT * CIN);   // 2 MB
  _Float16* xl = (_Float16*)alloc(sizeof(_Float16) * BB * NPT * CIN);   // 2 MB
  float* mx = ft;                                                        // alias (dead after k_dist_topk)
  float* sq = (float*)alloc(sizeof(float) * BB * NPT);                  // 64 KB
  float* p = (float*)alloc(sizeof(float) * BB * NPT * CO);              // 8 MB (becomes mn)
  float* v = (float*)alloc(sizeof(float) * BB * NPT * CO);              // 8 MB
  int* idx = (int*)alloc(sizeof(int) * BB * NPT * KK);                  // 1 MB
  float* psums = (float*)alloc(sizeof(float) * BB * (NPT / 32) * CO);   // 256 KB
  float* psqs = (float*)alloc(sizeof(float) * BB * (NPT / 32) * CO);    // 256 KB
  float* scale = (float*)alloc(sizeof(float) * CO);
  float* shift = (float*)alloc(sizeof(float) * CO);
  (void)ws_size; (void)in_sizes; (void)n_in; (void)out_size;

  hipLaunchKernelGGL(k_prep_pv, dim3(BB * (NPT / 64)), dim3(256), 0, stream,
                     x, W, bias, sq, xh, xl, p, v);
  hipLaunchKernelGGL(k_dist_topk, dim3(BB * (NPT / 16)), dim3(1024), 0, stream, xh, xl, sq, idx);
  hipLaunchKernelGGL(k_stats, dim3(BB * (NPT / 32)), dim3(256), 0, stream, p, v, idx, psums, psqs, mx);
  hipLaunchKernelGGL(k_final, dim3(CO), dim3(64), 0, stream, psums, psqs, gamma, beta, scale, shift);
  hipLaunchKernelGGL(k_out_fast, dim3(BB * (NPT / 32)), dim3(256), 0, stream, mx, p, scale, shift, out);
}